// Round 1
// 4247.868 us; speedup vs baseline: 1.3472x; 1.3472x over previous
//
#include <hip/hip_runtime.h>
#include <hip/hip_bf16.h>

// ---------------------------------------------------------------------------
// Longformer forward, MI355X. Round 2: replace latency-bound attn_global_k
// (96 blocks, per-lane strided gathers, 142 us) with split-K two-pass global
// attention (384-block partial + tiny merge).
// Constants: B=1 NW=8 SEG=511 S=4096 W=256 C=16 H=12 D=64 DM=768 FF=3072 L=12
// ---------------------------------------------------------------------------

typedef unsigned short u16;
typedef __attribute__((ext_vector_type(4))) float floatx4;
typedef __attribute__((ext_vector_type(4))) unsigned int uintx4;
typedef __attribute__((ext_vector_type(8))) short bf16x8;
typedef __attribute__((ext_vector_type(4))) u16 u16x4;

#define S_LEN 4096
#define QKVG_N 3840   // q(768) k(768) v(768) kg(768) vg(768)
#define NL 12

__device__ inline u16 f2bf(float x) {
    union { __hip_bfloat16 b; u16 u; } cv;
    cv.b = __float2bfloat16(x);
    return cv.u;
}
__device__ inline float bf2f(u16 u) {
    union { float f; unsigned int i; } c; c.i = ((unsigned int)u) << 16; return c.f;
}
__device__ inline float bflo(unsigned int u) {
    union { float f; unsigned int i; } c; c.i = u << 16; return c.f;
}
__device__ inline float bfhi(unsigned int u) {
    union { float f; unsigned int i; } c; c.i = u & 0xffff0000u; return c.f;
}
__device__ inline float gelu_f(float x) {
    float x3 = x * x * x;
    return 0.5f * x * (1.0f + tanhf(0.7978845608028654f * (x + 0.044715f * x3)));
}

#define GLDS16(g, l)                                                              \
    __builtin_amdgcn_global_load_lds(                                             \
        (const __attribute__((address_space(1))) unsigned int*)(g),               \
        (__attribute__((address_space(3))) unsigned int*)(l), 16, 0, 0)

// ---------------------------------------------------------------------------
// Weight prep: fp32 [K][N] -> bf16 [N][K] (transposed) + bias concat.
// ---------------------------------------------------------------------------
__global__ __launch_bounds__(256) void prep_weights_k(
    const float* __restrict__ Wq, const float* __restrict__ Wk, const float* __restrict__ Wv,
    const float* __restrict__ Wkg, const float* __restrict__ Wvg, const float* __restrict__ Wo,
    const float* __restrict__ W1, const float* __restrict__ W2,
    const float* __restrict__ bq, const float* __restrict__ bk, const float* __restrict__ bv,
    const float* __restrict__ bkg, const float* __restrict__ bvg,
    u16* __restrict__ wqkvgT, u16* __restrict__ woT, u16* __restrict__ w1T,
    u16* __restrict__ w2T, float* __restrict__ bcat)
{
    int bid = blockIdx.x;
    int t = threadIdx.x;
    if (bid >= 8064) {                       // bias concat tail: 3840 floats
        int i = (bid - 8064) * 256 + t;
        float v;
        if (i < 768)       v = bq[i];
        else if (i < 1536) v = bk[i - 768];
        else if (i < 2304) v = bv[i - 1536];
        else if (i < 3072) v = bkg[i - 2304];
        else               v = bvg[i - 3072];
        bcat[i] = v;
        return;
    }
    const float* src; u16* dst; int K, N, tile;
    if (bid < 2880) {
        int m = bid / 576; tile = bid % 576;
        src = (m == 0) ? Wq : (m == 1) ? Wk : (m == 2) ? Wv : (m == 3) ? Wkg : Wvg;
        dst = wqkvgT + (size_t)m * 589824;   // 768*768
        K = 768; N = 768;
    } else if (bid < 3456) { tile = bid - 2880; src = Wo; dst = woT; K = 768; N = 768; }
    else if (bid < 5760)   { tile = bid - 3456; src = W1; dst = w1T; K = 768; N = 3072; }
    else                   { tile = bid - 5760; src = W2; dst = w2T; K = 3072; N = 768; }

    int nt = N >> 5;
    int k0 = (tile / nt) << 5, n0 = (tile % nt) << 5;
    __shared__ float tb[32][33];
    int tx = t & 31, ty = t >> 5;            // ty: 0..7
    #pragma unroll
    for (int r = 0; r < 4; r++)
        tb[ty + r * 8][tx] = src[(size_t)(k0 + ty + r * 8) * N + n0 + tx];
    __syncthreads();
    #pragma unroll
    for (int r = 0; r < 4; r++) {
        int nn = ty + r * 8;
        dst[(size_t)(n0 + nn) * K + k0 + tx] = f2bf(tb[tx][nn]);
    }
}

// ---------------------------------------------------------------------------
// bf16 MFMA GEMM with global_load_lds staging (m97 pattern).
// ---------------------------------------------------------------------------
template <int ACT, int WF, int WB>
__global__ __launch_bounds__(256) void gemm_k(
    const u16* __restrict__ A, const u16* __restrict__ Bt,
    const float* __restrict__ bias,
    float* __restrict__ Cf, u16* __restrict__ Cb,
    int N, int K)
{
    __shared__ __align__(16) u16 As[128][32];
    __shared__ __align__(16) u16 Bs[128][32];
    int bm = blockIdx.x * 128, bn = blockIdx.y * 128;
    int t = threadIdx.x, lane = t & 63, wv = t >> 6;
    int wm = (wv >> 1) * 64, wn = (wv & 1) * 64;
    int arow = t >> 2, acol = (t & 3) * 8;     // staging: 64 rows x (4x8 bf16)
    int fr = lane & 15, fo = (lane >> 4) * 8;  // fragment row / k-offset

    floatx4 acc[4][4];
    #pragma unroll
    for (int i = 0; i < 4; i++)
        #pragma unroll
        for (int j = 0; j < 4; j++) acc[i][j] = (floatx4){0.f, 0.f, 0.f, 0.f};

    const int nk = K >> 5;
    for (int kt = 0; kt < nk; ++kt) {
        const u16* ag = A  + (size_t)(bm + arow) * K + kt * 32 + acol;
        const u16* bg = Bt + (size_t)(bn + arow) * K + kt * 32 + acol;
        GLDS16(ag,                   &As[arow][acol]);
        GLDS16(ag + (size_t)64 * K,  &As[arow + 64][acol]);
        GLDS16(bg,                   &Bs[arow][acol]);
        GLDS16(bg + (size_t)64 * K,  &Bs[arow + 64][acol]);
        __syncthreads();
        bf16x8 af[4], bfr[4];
        #pragma unroll
        for (int i = 0; i < 4; i++) af[i]  = *(const bf16x8*)&As[wm + i * 16 + fr][fo];
        #pragma unroll
        for (int i = 0; i < 4; i++) bfr[i] = *(const bf16x8*)&Bs[wn + i * 16 + fr][fo];
        #pragma unroll
        for (int i = 0; i < 4; i++)
            #pragma unroll
            for (int j = 0; j < 4; j++)
                acc[i][j] = __builtin_amdgcn_mfma_f32_16x16x32_bf16(af[i], bfr[j], acc[i][j], 0, 0, 0);
        __syncthreads();
    }

    int dr = (lane >> 4) * 4, dc = lane & 15;
    #pragma unroll
    for (int i = 0; i < 4; i++) {
        #pragma unroll
        for (int j = 0; j < 4; j++) {
            int r0 = bm + wm + i * 16 + dr;
            int cc = bn + wn + j * 16 + dc;
            float bsv = bias[cc];
            #pragma unroll
            for (int r = 0; r < 4; r++) {
                float v = acc[i][j][r] + bsv;
                if (ACT == 1) v = gelu_f(v);
                if (WF) Cf[(size_t)(r0 + r) * N + cc] = v;
                if (WB) Cb[(size_t)(r0 + r) * N + cc] = f2bf(v);
            }
        }
    }
}

// ---------------------------------------------------------------------------
// V transpose per layer: qkvg[s][1536+c] -> vTg[c][s]  (c in [0,768))
// ---------------------------------------------------------------------------
__global__ __launch_bounds__(256) void vtrans_k(
    const u16* __restrict__ qkvg, u16* __restrict__ vTg)
{
    int sb = blockIdx.x * 64, cb = blockIdx.y * 64;
    int t = threadIdx.x;
    __shared__ __align__(16) u16 lt[64][72];
    for (int c = t; c < 512; c += 256) {
        int sr = c >> 3, c0 = (c & 7) * 8;
        uintx4 d4 = *(const uintx4*)(qkvg + (size_t)(sb + sr) * QKVG_N + 1536 + cb + c0);
        const u16* u = (const u16*)&d4;
        #pragma unroll
        for (int j = 0; j < 8; ++j) lt[c0 + j][sr] = u[j];
    }
    __syncthreads();
    for (int c = t; c < 512; c += 256) {
        int cr = c >> 3, s0 = (c & 7) * 8;
        *(uintx4*)(vTg + (size_t)(cb + cr) * 4096 + sb + s0) = *(const uintx4*)&lt[cr][s0];
    }
}

// ---------------------------------------------------------------------------
// MFMA local banded attention + joint softmax with 8 global CLS keys.
// Block: (head, 64-query tile); 4 waves x 16 queries. Computes S^T via
// mfma(A=K, B=Q) so softmax state is per-lane-column; P round-trips through
// wave-private LDS into A-layout; PV uses pre-transposed V (vTg).
// Tile 0 = the 8 global CLS keys; tiles 1..9 = 64-key local band tiles.
// ---------------------------------------------------------------------------
__global__ __launch_bounds__(256) void attn_local_k(
    const u16* __restrict__ qkvg, const u16* __restrict__ vTg, u16* __restrict__ aob)
{
    const int hh = blockIdx.x, qb = blockIdx.y;
    const int t = threadIdx.x, lane = t & 63, w = t >> 6;
    const int g = lane >> 4, qi = lane & 15;
    __shared__ __align__(16) u16 ks[64][72];
    __shared__ __align__(16) u16 vt[64][72];
    __shared__ __align__(16) u16 pbuf[4][16][40];

    const int q0w = qb * 64 + w * 16;
    const int sq = q0w + qi;                 // softmax-column query (per lane)

    bf16x8 qf0, qf1;                          // Q B-operand frags (2 k-steps)
    {
        const u16* qp = qkvg + (size_t)(q0w + qi) * QKVG_N + hh * 64 + g * 8;
        qf0 = *(const bf16x8*)qp;
        qf1 = *(const bf16x8*)(qp + 32);
    }

    floatx4 acc[4];
    #pragma unroll
    for (int i = 0; i < 4; i++) acc[i] = (floatx4){0.f, 0.f, 0.f, 0.f};
    float mrun = -1e30f, lrun = 0.f;

    for (int tile = 0; tile <= 9; ++tile) {
        const int kbase = qb * 64 - 256 + (tile - 1) * 64;
        if (tile > 0 && (kbase < -63 || kbase >= S_LEN)) continue;  // uniform skip
        __syncthreads();
        if (tile == 0) {
            // zero vt (avoid NaN junk x P=0), then fill 8 global K/V columns
            for (int i = t; i < 576; i += 256) ((uintx4*)vt)[i] = (uintx4){0, 0, 0, 0};
            __syncthreads();
            if (t < 64) {
                int gg = t >> 3, d0 = (t & 7) * 8;
                *(uintx4*)&ks[gg][d0] =
                    *(const uintx4*)(qkvg + (size_t)(gg * 512) * QKVG_N + 768 + hh * 64 + d0);
            }
            for (int e = t; e < 512; e += 256) {
                int d = e >> 3, gg = e & 7;
                vt[d][gg] = vTg[(size_t)(hh * 64 + d) * 4096 + gg * 512];
            }
        } else {
            for (int c = t; c < 512; c += 256) {
                int r = c >> 3, c0 = (c & 7) * 8;
                int row = kbase + r; row = row < 0 ? 0 : (row > 4095 ? 4095 : row);
                *(uintx4*)&ks[r][c0] =
                    *(const uintx4*)(qkvg + (size_t)row * QKVG_N + 768 + hh * 64 + c0);
                int gc = kbase + c0; gc = gc < 0 ? 0 : (gc > 4088 ? 4088 : gc);
                *(uintx4*)&vt[r][c0] =
                    *(const uintx4*)(vTg + (size_t)(hh * 64 + r) * 4096 + gc);
            }
        }
        __syncthreads();

        const bool gt = (tile == 0);
        const int ng = gt ? 1 : 2;
        for (int kg2 = 0; kg2 < ng; ++kg2) {
            floatx4 sf[2];
            sf[1] = (floatx4){0.f, 0.f, 0.f, 0.f};
            {
                bf16x8 ka0 = *(const bf16x8*)&ks[kg2 * 32 + qi][g * 8];
                bf16x8 ka1 = *(const bf16x8*)&ks[kg2 * 32 + qi][32 + g * 8];
                floatx4 z = (floatx4){0.f, 0.f, 0.f, 0.f};
                z = __builtin_amdgcn_mfma_f32_16x16x32_bf16(ka0, qf0, z, 0, 0, 0);
                sf[0] = __builtin_amdgcn_mfma_f32_16x16x32_bf16(ka1, qf1, z, 0, 0, 0);
            }
            if (!gt) {
                bf16x8 kb0 = *(const bf16x8*)&ks[kg2 * 32 + 16 + qi][g * 8];
                bf16x8 kb1 = *(const bf16x8*)&ks[kg2 * 32 + 16 + qi][32 + g * 8];
                floatx4 z = (floatx4){0.f, 0.f, 0.f, 0.f};
                z = __builtin_amdgcn_mfma_f32_16x16x32_bf16(kb0, qf0, z, 0, 0, 0);
                sf[1] = __builtin_amdgcn_mfma_f32_16x16x32_bf16(kb1, qf1, z, 0, 0, 0);
            }
            // scores: lane holds keys kl = kg2*32 + f*16 + g*4 + r for query sq
            float p8[8];
            float mloc = -1e30f;
            #pragma unroll
            for (int f = 0; f < 2; ++f)
                #pragma unroll
                for (int r = 0; r < 4; ++r) {
                    int kl = kg2 * 32 + f * 16 + g * 4 + r;
                    bool valid;
                    if (gt) valid = (kl < 8);
                    else {
                        int kp = kbase + kl, dd = kp - sq;
                        valid = (kp >= 0) & (kp < S_LEN) & (dd <= 256) & (dd >= -256);
                    }
                    float sc = valid ? sf[f][r] * 0.125f : -1e30f;
                    p8[f * 4 + r] = sc;
                    mloc = fmaxf(mloc, sc);
                }
            mloc = fmaxf(mloc, __shfl_xor(mloc, 16));
            mloc = fmaxf(mloc, __shfl_xor(mloc, 32));
            float mnew = fmaxf(mrun, mloc);
            float alpha = __expf(mrun - mnew);
            mrun = mnew;
            float ls = 0.f;
            #pragma unroll
            for (int i = 0; i < 8; ++i) { float p = __expf(p8[i] - mnew); p8[i] = p; ls += p; }
            ls += __shfl_xor(ls, 16);
            ls += __shfl_xor(ls, 32);
            lrun = lrun * alpha + ls;
            // pack P -> wave-private LDS (row q=qi, cols f*16 + g*4 ..+3)
            u16x4 w0, w1;
            #pragma unroll
            for (int r = 0; r < 4; ++r) { w0[r] = f2bf(p8[r]); w1[r] = f2bf(p8[4 + r]); }
            *(u16x4*)&pbuf[w][qi][g * 4] = w0;
            *(u16x4*)&pbuf[w][qi][16 + g * 4] = w1;
            // rescale acc rows (row m = g*4+r, alpha lives at lane m)
            float al[4];
            #pragma unroll
            for (int r = 0; r < 4; ++r) al[r] = __shfl(alpha, g * 4 + r);
            #pragma unroll
            for (int dt = 0; dt < 4; ++dt)
                #pragma unroll
                for (int r = 0; r < 4; ++r) acc[dt][r] *= al[r];
            // P A-frag + PV MFMAs
            bf16x8 pf = *(const bf16x8*)&pbuf[w][qi][g * 8];
            #pragma unroll
            for (int dt = 0; dt < 4; ++dt) {
                bf16x8 vb = *(const bf16x8*)&vt[dt * 16 + qi][kg2 * 32 + g * 8];
                acc[dt] = __builtin_amdgcn_mfma_f32_16x16x32_bf16(pf, vb, acc[dt], 0, 0, 0);
            }
        }
    }

    float inv = 1.f / lrun;
    float li[4];
    #pragma unroll
    for (int r = 0; r < 4; ++r) li[r] = __shfl(inv, g * 4 + r);
    #pragma unroll
    for (int dt = 0; dt < 4; ++dt)
        #pragma unroll
        for (int r = 0; r < 4; ++r) {
            int s = q0w + g * 4 + r;
            aob[(size_t)s * 768 + hh * 64 + dt * 16 + qi] = f2bf(acc[dt][r] * li[r]);
        }
}

// ---------------------------------------------------------------------------
// LayerNorm helpers
// ---------------------------------------------------------------------------
#define BLOCK_MEANVAR(sum, sq, mean, inv)                                        \
    {                                                                            \
        for (int o_ = 32; o_ > 0; o_ >>= 1) {                                    \
            sum += __shfl_down(sum, o_); sq += __shfl_down(sq, o_);              \
        }                                                                        \
        __shared__ float rs_[4], rq_[4];                                         \
        if ((threadIdx.x & 63) == 0) { rs_[threadIdx.x >> 6] = sum; rq_[threadIdx.x >> 6] = sq; } \
        __syncthreads();                                                         \
        float S_ = rs_[0] + rs_[1] + rs_[2] + rs_[3];                            \
        float Q_ = rq_[0] + rq_[1] + rq_[2] + rq_[3];                            \
        mean = S_ * (1.f / 768.f);                                               \
        float var_ = Q_ * (1.f / 768.f) - mean * mean;                           \
        inv = rsqrtf(var_ + 1e-5f);                                              \
    }

__global__ __launch_bounds__(256) void embed_ln_k(
    const int* __restrict__ x, const float* __restrict__ wemb, const float* __restrict__ pemb,
    const float* __restrict__ gs, const float* __restrict__ gb,
    float* __restrict__ hf, u16* __restrict__ hb)
{
    int s = blockIdx.x, t = threadIdx.x;
    int w = s >> 9, p = s & 511;
    int id = (p == 0) ? 0 : x[w * 511 + p - 1];
    float v[3], sum = 0.f, sq = 0.f;
    #pragma unroll
    for (int r = 0; r < 3; r++) {
        int d = t + r * 256;
        float e = wemb[(size_t)id * 768 + d] + pemb[(size_t)s * 768 + d];
        v[r] = e; sum += e; sq += e * e;
    }
    float mean, inv;
    BLOCK_MEANVAR(sum, sq, mean, inv)
    #pragma unroll
    for (int r = 0; r < 3; r++) {
        int d = t + r * 256;
        float y = (v[r] - mean) * inv * gs[d] + gb[d];
        hf[(size_t)s * 768 + d] = y;
        hb[(size_t)s * 768 + d] = f2bf(y);
    }
}

__global__ __launch_bounds__(256) void ln_resid_k(
    const float* __restrict__ xa, const float* __restrict__ xb,
    const float* __restrict__ gs, const float* __restrict__ gb,
    float* __restrict__ of, u16* __restrict__ ob)
{
    int s = blockIdx.x, t = threadIdx.x;
    const float* pa = xa + (size_t)s * 768;
    const float* pb = xb + (size_t)s * 768;
    float v[3], sum = 0.f, sq = 0.f;
    #pragma unroll
    for (int r = 0; r < 3; r++) {
        int d = t + r * 256;
        float e = pa[d] + pb[d];
        v[r] = e; sum += e; sq += e * e;
    }
    float mean, inv;
    BLOCK_MEANVAR(sum, sq, mean, inv)
    #pragma unroll
    for (int r = 0; r < 3; r++) {
        int d = t + r * 256;
        float y = (v[r] - mean) * inv * gs[d] + gb[d];
        of[(size_t)s * 768 + d] = y;
        ob[(size_t)s * 768 + d] = f2bf(y);
    }
}

// qg = (h[GPOS] @ Wqg + bqg) * SCALE   -> [8][768] fp32
__global__ __launch_bounds__(256) void qg_proj_k(
    const float* __restrict__ hf, const float* __restrict__ Wqg,
    const float* __restrict__ bqg, float* __restrict__ qgf)
{
    int g = blockIdx.x;
    int col = blockIdx.y * 256 + threadIdx.x;
    __shared__ float hsh[768];
    for (int i = threadIdx.x; i < 768; i += 256) hsh[i] = hf[(size_t)(g * 512) * 768 + i];
    __syncthreads();
    float a = 0.f;
    #pragma unroll 4
    for (int k = 0; k < 768; k++) a += hsh[k] * Wqg[(size_t)k * 768 + col];
    qgf[g * 768 + col] = (a + bqg[col]) * 0.125f;
}

// ---------------------------------------------------------------------------
// Global-token attention, pass 1: split-K partials.
// grid (12 heads, 32 key-chunks of 128), 256 threads.
// Per block: stage Kg/Vg chunk rows -> LDS (coalesced 16B), score all 8
// global queries, chunk-local softmax (m,l), partial PV -> workspace.
// ---------------------------------------------------------------------------
__global__ __launch_bounds__(256) void attn_gpart_k(
    const float* __restrict__ qgf, const u16* __restrict__ qkvg,
    float* __restrict__ pacc, float* __restrict__ pm, float* __restrict__ pl)
{
    const int hh = blockIdx.x, ck = blockIdx.y;
    const int t = threadIdx.x;
    __shared__ float qs[8][64];
    __shared__ __align__(16) u16 ks[128][72];   // +8 pad: stage writes c-free
    __shared__ __align__(16) u16 vs[128][64];   // read d-major -> conflict-free
    __shared__ float sc[8][128];
    __shared__ float mred[8], lred[8];

    for (int i = t; i < 512; i += 256)
        qs[i >> 6][i & 63] = qgf[(i >> 6) * 768 + hh * 64 + (i & 63)];
    const int s0 = ck * 128;
    for (int u = t; u < 1024; u += 256) {
        int r = u >> 3, c = u & 7;
        const u16* src = qkvg + (size_t)(s0 + r) * QKVG_N + hh * 64 + c * 8;
        *(uintx4*)&ks[r][c * 8] = *(const uintx4*)(src + 2304);
        *(uintx4*)&vs[r][c * 8] = *(const uintx4*)(src + 3072);
    }
    __syncthreads();

    // scores: thread (key = t&127) computes 4 queries (t>>7 selects 0-3 / 4-7)
    {
        int key = t & 127, q0 = (t >> 7) * 4;
        float a[4] = {0.f, 0.f, 0.f, 0.f};
        #pragma unroll
        for (int c = 0; c < 8; ++c) {
            uintx4 pk = *(const uintx4*)&ks[key][c * 8];
            const u16* uu = (const u16*)&pk;
            #pragma unroll
            for (int e = 0; e < 8; ++e) {
                float kv = bf2f(uu[e]);
                #pragma unroll
                for (int q = 0; q < 4; ++q) a[q] += kv * qs[q0 + q][c * 8 + e];
            }
        }
        #pragma unroll
        for (int q = 0; q < 4; ++q) sc[q0 + q][key] = a[q];
    }
    __syncthreads();

    // chunk softmax: q = t>>5, 32 lanes/query, 4 keys each
    {
        int q = t >> 5, lq = t & 31;
        float m = -1e30f;
        #pragma unroll
        for (int i = 0; i < 4; ++i) m = fmaxf(m, sc[q][lq + i * 32]);
        #pragma unroll
        for (int o = 1; o < 32; o <<= 1) m = fmaxf(m, __shfl_xor(m, o));
        float ls = 0.f;
        #pragma unroll
        for (int i = 0; i < 4; ++i) {
            float p = __expf(sc[q][lq + i * 32] - m);
            sc[q][lq + i * 32] = p; ls += p;
        }
        #pragma unroll
        for (int o = 1; o < 32; o <<= 1) ls += __shfl_xor(ls, o);
        if (lq == 0) { mred[q] = m; lred[q] = ls; }
    }
    __syncthreads();

    // partial PV: thread (d = t&63, qb = t>>6) -> o[qb][d], o[qb+4][d]
    {
        int d = t & 63, qb = t >> 6;
        float a0 = 0.f, a1 = 0.f;
        #pragma unroll 4
        for (int s = 0; s < 128; ++s) {
            float v = bf2f(vs[s][d]);
            a0 += sc[qb][s] * v;
            a1 += sc[qb + 4][s] * v;
        }
        float* pb = pacc + (((size_t)hh * 32 + ck) * 8) * 64;
        pb[qb * 64 + d] = a0;
        pb[(qb + 4) * 64 + d] = a1;
        if (t < 8) {
            pm[((size_t)hh * 32 + ck) * 8 + t] = mred[t];
            pl[((size_t)hh * 32 + ck) * 8 + t] = lred[t];
        }
    }
}

// Pass 2: merge 32 chunk partials per (head, query), overwrite GPOS rows.
__global__ __launch_bounds__(64) void attn_gred_k(
    const float* __restrict__ pacc, const float* __restrict__ pm,
    const float* __restrict__ pl, u16* __restrict__ aob)
{
    int hh = blockIdx.x, gq = blockIdx.y;
    int d = threadIdx.x;
    float M = -1e30f;
    #pragma unroll 4
    for (int c = 0; c < 32; ++c)
        M = fmaxf(M, pm[((size_t)hh * 32 + c) * 8 + gq]);
    float L = 0.f, o = 0.f;
    #pragma unroll 4
    for (int c = 0; c < 32; ++c) {
        float w = __expf(pm[((size_t)hh * 32 + c) * 8 + gq] - M);
        L += pl[((size_t)hh * 32 + c) * 8 + gq] * w;
        o += w * pacc[(((size_t)hh * 32 + c) * 8 + gq) * 64 + d];
    }
    aob[(size_t)(gq * 512) * 768 + hh * 64 + d] = f2bf(o / L);
}

__global__ __launch_bounds__(128) void head_k(
    const float* __restrict__ hf, const float* __restrict__ Wout,
    const float* __restrict__ bout, float* __restrict__ out)
{
    int g = blockIdx.x, n = threadIdx.x;
    __shared__ float hsh[768];
    for (int i = n; i < 768; i += 128) hsh[i] = hf[(size_t)(g * 512) * 768 + i];
    __syncthreads();
    float a = 0.f;
    #pragma unroll 4
    for (int k = 0; k < 768; k++) a += hsh[k] * Wout[k * 128 + n];
    out[g * 128 + n] = a + bout[n];
}

// ---------------------------------------------------------------------------
extern "C" void kernel_launch(void* const* d_in, const int* in_sizes, int n_in,
                              void* d_out, int out_size, void* d_ws, size_t ws_size,
                              hipStream_t stream)
{
    (void)in_sizes; (void)n_in; (void)out_size; (void)ws_size;
    const int*   x    = (const int*)  d_in[0];
    const float* wemb = (const float*)d_in[1];
    const float* pemb = (const float*)d_in[2];
    const float* elns = (const float*)d_in[3];
    const float* elnb = (const float*)d_in[4];
    const float* Wq   = (const float*)d_in[5];
    const float* bq   = (const float*)d_in[6];
    const float* Wk   = (const float*)d_in[7];
    const float* bk   = (const float*)d_in[8];
    const float* Wv   = (const float*)d_in[9];
    const float* bv   = (const float*)d_in[10];
    const float* Wo   = (const float*)d_in[11];
    const float* bo   = (const float*)d_in[12];
    const float* Wqg  = (const float*)d_in[13];
    const float* bqg  = (const float*)d_in[14];
    const float* Wkg  = (const float*)d_in[15];
    const float* bkg  = (const float*)d_in[16];
    const float* Wvg  = (const float*)d_in[17];
    const float* bvg  = (const float*)d_in[18];
    const float* l1s  = (const float*)d_in[19];
    const float* l1b  = (const float*)d_in[20];
    const float* W1   = (const float*)d_in[21];
    const float* b1   = (const float*)d_in[22];
    const float* W2   = (const float*)d_in[23];
    const float* b2   = (const float*)d_in[24];
    const float* l2s  = (const float*)d_in[25];
    const float* l2b  = (const float*)d_in[26];
    const float* Wout = (const float*)d_in[27];
    const float* boutp= (const float*)d_in[28];

    char* W = (char*)d_ws;
    float* hf    = (float*)(W);                  // [4096][768]  fp32
    u16*   hb    = (u16*)  (W + 12582912);       // [4096][768]  bf16
    u16*   qkvg  = (u16*)  (W + 18874368);       // [4096][3840] bf16
    u16*   vTg   = (u16*)  (W + 50331648);       // [768][4096]  bf16
    u16*   aob   = (u16*)  (W + 56623104);       // [4096][768]  bf16
    float* yf    = (float*)(W + 62914560);       // [4096][768]  fp32
    u16*   ff1b  = (u16*)  (W + 75497472);       // [4096][3072] bf16
    float* ff2f  = (float*)(W + 100663296);      // [4096][768]  fp32
    float* qgf   = (float*)(W + 113246208);      // [8][768]     fp32
    float* bcat  = (float*)(W + 113270784);      // [3840]       fp32
    u16*   wT    = (u16*)  (W + 113286144);      // bf16 transposed weights
    u16* wqkvgT = wT;                            // [3840][768]
    u16* woT    = wT + 2949120;                  // [768][768]
    u16* w1T    = wT + 3538944;                  // [3072][768]
    u16* w2T    = wT + 5898240;                  // [768][3072]
    float* pacc = (float*)(W + 129801216);       // [12][32][8][64] fp32
    float* pmw  = (float*)(W + 130587648);       // [12][32][8]     fp32
    float* plw  = (float*)(W + 130599936);       // [12][32][8]     fp32

    embed_ln_k<<<4096, 256, 0, stream>>>(x, wemb, pemb, elns, elnb, hf, hb);

    for (int l = 0; l < NL; ++l) {
        const float* Wq_l  = Wq  + (size_t)l * 768 * 768;
        const float* Wk_l  = Wk  + (size_t)l * 768 * 768;
        const float* Wv_l  = Wv  + (size_t)l * 768 * 768;
        const float* Wo_l  = Wo  + (size_t)l * 768 * 768;
        const float* Wqg_l = Wqg + (size_t)l * 768 * 768;
        const float* Wkg_l = Wkg + (size_t)l * 768 * 768;
        const float* Wvg_l = Wvg + (size_t)l * 768 * 768;
        const float* W1_l  = W1  + (size_t)l * 768 * 3072;
        const float* W2_l  = W2  + (size_t)l * 3072 * 768;
        const float* bq_l  = bq  + (size_t)l * 768;
        const float* bk_l  = bk  + (size_t)l * 768;
        const float* bv_l  = bv  + (size_t)l * 768;
        const float* bo_l  = bo  + (size_t)l * 768;
        const float* bqg_l = bqg + (size_t)l * 768;
        const float* bkg_l = bkg + (size_t)l * 768;
        const float* bvg_l = bvg + (size_t)l * 768;
        const float* b1_l  = b1  + (size_t)l * 3072;
        const float* b2_l  = b2  + (size_t)l * 768;
        const float* l1s_l = l1s + (size_t)l * 768;
        const float* l1b_l = l1b + (size_t)l * 768;
        const float* l2s_l = l2s + (size_t)l * 768;
        const float* l2b_l = l2b + (size_t)l * 768;

        prep_weights_k<<<8079, 256, 0, stream>>>(
            Wq_l, Wk_l, Wv_l, Wkg_l, Wvg_l, Wo_l, W1_l, W2_l,
            bq_l, bk_l, bv_l, bkg_l, bvg_l,
            wqkvgT, woT, w1T, w2T, bcat);

        // fused q/k/v/kg/vg projection -> bf16 [4096][3840]
        gemm_k<0, 0, 1><<<dim3(32, 30), 256, 0, stream>>>(
            hb, wqkvgT, bcat, (float*)nullptr, qkvg, QKVG_N, 768);

        vtrans_k<<<dim3(64, 12), 256, 0, stream>>>(qkvg, vTg);

        attn_local_k<<<dim3(12, 64), 256, 0, stream>>>(qkvg, vTg, aob);

        qg_proj_k<<<dim3(8, 3), 256, 0, stream>>>(hf, Wqg_l, bqg_l, qgf);
        attn_gpart_k<<<dim3(12, 32), 256, 0, stream>>>(qgf, qkvg, pacc, pmw, plw);
        attn_gred_k<<<dim3(12, 8), 64, 0, stream>>>(pacc, pmw, plw, aob);

        gemm_k<0, 1, 0><<<dim3(32, 6), 256, 0, stream>>>(
            aob, woT, bo_l, yf, (u16*)nullptr, 768, 768);
        ln_resid_k<<<4096, 256, 0, stream>>>(hf, yf, l1s_l, l1b_l, hf, hb);

        gemm_k<1, 0, 1><<<dim3(32, 24), 256, 0, stream>>>(
            hb, w1T, b1_l, (float*)nullptr, ff1b, 3072, 768);
        gemm_k<0, 1, 0><<<dim3(32, 6), 256, 0, stream>>>(
            ff1b, w2T, b2_l, ff2f, (u16*)nullptr, 768, 3072);
        ln_resid_k<<<4096, 256, 0, stream>>>(hf, ff2f, l2s_l, l2b_l, hf, hb);
    }

    head_k<<<8, 128, 0, stream>>>(hf, Wout, boutp, (float*)d_out);
}

// Round 2
// 3206.939 us; speedup vs baseline: 1.7844x; 1.3246x over previous
//
#include <hip/hip_runtime.h>
#include <hip/hip_bf16.h>

// ---------------------------------------------------------------------------
// Longformer forward, MI355X. Round 3: fold qg projection into the fused
// qkvg MFMA GEMM (kills the 93us latency-bound qg_proj_k GEMV).
// Constants: B=1 NW=8 SEG=511 S=4096 W=256 C=16 H=12 D=64 DM=768 FF=3072 L=12
// ---------------------------------------------------------------------------

typedef unsigned short u16;
typedef __attribute__((ext_vector_type(4))) float floatx4;
typedef __attribute__((ext_vector_type(4))) unsigned int uintx4;
typedef __attribute__((ext_vector_type(8))) short bf16x8;
typedef __attribute__((ext_vector_type(4))) u16 u16x4;

#define S_LEN 4096
#define QKVG_N 4608   // q(0) k(768) v(1536) kg(2304) vg(3072) qg(3840)
#define NL 12

__device__ inline u16 f2bf(float x) {
    union { __hip_bfloat16 b; u16 u; } cv;
    cv.b = __float2bfloat16(x);
    return cv.u;
}
__device__ inline float bf2f(u16 u) {
    union { float f; unsigned int i; } c; c.i = ((unsigned int)u) << 16; return c.f;
}
__device__ inline float gelu_f(float x) {
    float x3 = x * x * x;
    return 0.5f * x * (1.0f + tanhf(0.7978845608028654f * (x + 0.044715f * x3)));
}

#define GLDS16(g, l)                                                              \
    __builtin_amdgcn_global_load_lds(                                             \
        (const __attribute__((address_space(1))) unsigned int*)(g),               \
        (__attribute__((address_space(3))) unsigned int*)(l), 16, 0, 0)

// ---------------------------------------------------------------------------
// Weight prep: fp32 [K][N] -> bf16 [N][K] (transposed) + bias concat.
// wqkvgT holds q,k,v,kg,vg,qg (6 x 768x768).
// ---------------------------------------------------------------------------
__global__ __launch_bounds__(256) void prep_weights_k(
    const float* __restrict__ Wq, const float* __restrict__ Wk, const float* __restrict__ Wv,
    const float* __restrict__ Wkg, const float* __restrict__ Wvg, const float* __restrict__ Wqg,
    const float* __restrict__ Wo, const float* __restrict__ W1, const float* __restrict__ W2,
    const float* __restrict__ bq, const float* __restrict__ bk, const float* __restrict__ bv,
    const float* __restrict__ bkg, const float* __restrict__ bvg, const float* __restrict__ bqg,
    u16* __restrict__ wqkvgT, u16* __restrict__ woT, u16* __restrict__ w1T,
    u16* __restrict__ w2T, float* __restrict__ bcat)
{
    int bid = blockIdx.x;
    int t = threadIdx.x;
    if (bid >= 8640) {                       // bias concat tail: 4608 floats
        int i = (bid - 8640) * 256 + t;
        float v;
        if (i < 768)       v = bq[i];
        else if (i < 1536) v = bk[i - 768];
        else if (i < 2304) v = bv[i - 1536];
        else if (i < 3072) v = bkg[i - 2304];
        else if (i < 3840) v = bvg[i - 3072];
        else               v = bqg[i - 3840];
        bcat[i] = v;
        return;
    }
    const float* src; u16* dst; int K, N, tile;
    if (bid < 3456) {
        int m = bid / 576; tile = bid % 576;
        src = (m == 0) ? Wq : (m == 1) ? Wk : (m == 2) ? Wv :
              (m == 3) ? Wkg : (m == 4) ? Wvg : Wqg;
        dst = wqkvgT + (size_t)m * 589824;   // 768*768
        K = 768; N = 768;
    } else if (bid < 4032) { tile = bid - 3456; src = Wo; dst = woT; K = 768; N = 768; }
    else if (bid < 6336)   { tile = bid - 4032; src = W1; dst = w1T; K = 768; N = 3072; }
    else                   { tile = bid - 6336; src = W2; dst = w2T; K = 3072; N = 768; }

    int nt = N >> 5;
    int k0 = (tile / nt) << 5, n0 = (tile % nt) << 5;
    __shared__ float tb[32][33];
    int tx = t & 31, ty = t >> 5;            // ty: 0..7
    #pragma unroll
    for (int r = 0; r < 4; r++)
        tb[ty + r * 8][tx] = src[(size_t)(k0 + ty + r * 8) * N + n0 + tx];
    __syncthreads();
    #pragma unroll
    for (int r = 0; r < 4; r++) {
        int nn = ty + r * 8;
        dst[(size_t)(n0 + nn) * K + k0 + tx] = f2bf(tb[tx][nn]);
    }
}

// ---------------------------------------------------------------------------
// bf16 MFMA GEMM with global_load_lds staging (m97 pattern).
// SKIPQG: for the fused projection, N-tiles >= 30 (qg columns) are only
// needed at M-tiles containing a GPOS row (bm % 512 == 0).
// ---------------------------------------------------------------------------
template <int ACT, int WF, int WB, int SKIPQG>
__global__ __launch_bounds__(256) void gemm_k(
    const u16* __restrict__ A, const u16* __restrict__ Bt,
    const float* __restrict__ bias,
    float* __restrict__ Cf, u16* __restrict__ Cb,
    int N, int K)
{
    if (SKIPQG && blockIdx.y >= 30 && (blockIdx.x & 3) != 0) return;
    __shared__ __align__(16) u16 As[128][32];
    __shared__ __align__(16) u16 Bs[128][32];
    int bm = blockIdx.x * 128, bn = blockIdx.y * 128;
    int t = threadIdx.x, lane = t & 63, wv = t >> 6;
    int wm = (wv >> 1) * 64, wn = (wv & 1) * 64;
    int arow = t >> 2, acol = (t & 3) * 8;     // staging: 64 rows x (4x8 bf16)
    int fr = lane & 15, fo = (lane >> 4) * 8;  // fragment row / k-offset

    floatx4 acc[4][4];
    #pragma unroll
    for (int i = 0; i < 4; i++)
        #pragma unroll
        for (int j = 0; j < 4; j++) acc[i][j] = (floatx4){0.f, 0.f, 0.f, 0.f};

    const int nk = K >> 5;
    for (int kt = 0; kt < nk; ++kt) {
        const u16* ag = A  + (size_t)(bm + arow) * K + kt * 32 + acol;
        const u16* bg = Bt + (size_t)(bn + arow) * K + kt * 32 + acol;
        GLDS16(ag,                   &As[arow][acol]);
        GLDS16(ag + (size_t)64 * K,  &As[arow + 64][acol]);
        GLDS16(bg,                   &Bs[arow][acol]);
        GLDS16(bg + (size_t)64 * K,  &Bs[arow + 64][acol]);
        __syncthreads();
        bf16x8 af[4], bfr[4];
        #pragma unroll
        for (int i = 0; i < 4; i++) af[i]  = *(const bf16x8*)&As[wm + i * 16 + fr][fo];
        #pragma unroll
        for (int i = 0; i < 4; i++) bfr[i] = *(const bf16x8*)&Bs[wn + i * 16 + fr][fo];
        #pragma unroll
        for (int i = 0; i < 4; i++)
            #pragma unroll
            for (int j = 0; j < 4; j++)
                acc[i][j] = __builtin_amdgcn_mfma_f32_16x16x32_bf16(af[i], bfr[j], acc[i][j], 0, 0, 0);
        __syncthreads();
    }

    int dr = (lane >> 4) * 4, dc = lane & 15;
    #pragma unroll
    for (int i = 0; i < 4; i++) {
        #pragma unroll
        for (int j = 0; j < 4; j++) {
            int r0 = bm + wm + i * 16 + dr;
            int cc = bn + wn + j * 16 + dc;
            float bsv = bias[cc];
            #pragma unroll
            for (int r = 0; r < 4; r++) {
                float v = acc[i][j][r] + bsv;
                if (ACT == 1) v = gelu_f(v);
                if (WF) Cf[(size_t)(r0 + r) * N + cc] = v;
                if (WB) Cb[(size_t)(r0 + r) * N + cc] = f2bf(v);
            }
        }
    }
}

// ---------------------------------------------------------------------------
// V transpose per layer: qkvg[s][1536+c] -> vTg[c][s]  (c in [0,768))
// ---------------------------------------------------------------------------
__global__ __launch_bounds__(256) void vtrans_k(
    const u16* __restrict__ qkvg, u16* __restrict__ vTg)
{
    int sb = blockIdx.x * 64, cb = blockIdx.y * 64;
    int t = threadIdx.x;
    __shared__ __align__(16) u16 lt[64][72];
    for (int c = t; c < 512; c += 256) {
        int sr = c >> 3, c0 = (c & 7) * 8;
        uintx4 d4 = *(const uintx4*)(qkvg + (size_t)(sb + sr) * QKVG_N + 1536 + cb + c0);
        const u16* u = (const u16*)&d4;
        #pragma unroll
        for (int j = 0; j < 8; ++j) lt[c0 + j][sr] = u[j];
    }
    __syncthreads();
    for (int c = t; c < 512; c += 256) {
        int cr = c >> 3, s0 = (c & 7) * 8;
        *(uintx4*)(vTg + (size_t)(cb + cr) * 4096 + sb + s0) = *(const uintx4*)&lt[cr][s0];
    }
}

// ---------------------------------------------------------------------------
// MFMA local banded attention + joint softmax with 8 global CLS keys.
// Block: (head, 64-query tile); 4 waves x 16 queries. Computes S^T via
// mfma(A=K, B=Q) so softmax state is per-lane-column; P round-trips through
// wave-private LDS into A-layout; PV uses pre-transposed V (vTg).
// Tile 0 = the 8 global CLS keys; tiles 1..9 = 64-key local band tiles.
// ---------------------------------------------------------------------------
__global__ __launch_bounds__(256) void attn_local_k(
    const u16* __restrict__ qkvg, const u16* __restrict__ vTg, u16* __restrict__ aob)
{
    const int hh = blockIdx.x, qb = blockIdx.y;
    const int t = threadIdx.x, lane = t & 63, w = t >> 6;
    const int g = lane >> 4, qi = lane & 15;
    __shared__ __align__(16) u16 ks[64][72];
    __shared__ __align__(16) u16 vt[64][72];
    __shared__ __align__(16) u16 pbuf[4][16][40];

    const int q0w = qb * 64 + w * 16;
    const int sq = q0w + qi;                 // softmax-column query (per lane)

    bf16x8 qf0, qf1;                          // Q B-operand frags (2 k-steps)
    {
        const u16* qp = qkvg + (size_t)(q0w + qi) * QKVG_N + hh * 64 + g * 8;
        qf0 = *(const bf16x8*)qp;
        qf1 = *(const bf16x8*)(qp + 32);
    }

    floatx4 acc[4];
    #pragma unroll
    for (int i = 0; i < 4; i++) acc[i] = (floatx4){0.f, 0.f, 0.f, 0.f};
    float mrun = -1e30f, lrun = 0.f;

    for (int tile = 0; tile <= 9; ++tile) {
        const int kbase = qb * 64 - 256 + (tile - 1) * 64;
        if (tile > 0 && (kbase < -63 || kbase >= S_LEN)) continue;  // uniform skip
        __syncthreads();
        if (tile == 0) {
            // zero vt (avoid NaN junk x P=0), then fill 8 global K/V columns
            for (int i = t; i < 576; i += 256) ((uintx4*)vt)[i] = (uintx4){0, 0, 0, 0};
            __syncthreads();
            if (t < 64) {
                int gg = t >> 3, d0 = (t & 7) * 8;
                *(uintx4*)&ks[gg][d0] =
                    *(const uintx4*)(qkvg + (size_t)(gg * 512) * QKVG_N + 768 + hh * 64 + d0);
            }
            for (int e = t; e < 512; e += 256) {
                int d = e >> 3, gg = e & 7;
                vt[d][gg] = vTg[(size_t)(hh * 64 + d) * 4096 + gg * 512];
            }
        } else {
            for (int c = t; c < 512; c += 256) {
                int r = c >> 3, c0 = (c & 7) * 8;
                int row = kbase + r; row = row < 0 ? 0 : (row > 4095 ? 4095 : row);
                *(uintx4*)&ks[r][c0] =
                    *(const uintx4*)(qkvg + (size_t)row * QKVG_N + 768 + hh * 64 + c0);
                int gc = kbase + c0; gc = gc < 0 ? 0 : (gc > 4088 ? 4088 : gc);
                *(uintx4*)&vt[r][c0] =
                    *(const uintx4*)(vTg + (size_t)(hh * 64 + r) * 4096 + gc);
            }
        }
        __syncthreads();

        const bool gt = (tile == 0);
        const int ng = gt ? 1 : 2;
        for (int kg2 = 0; kg2 < ng; ++kg2) {
            floatx4 sf[2];
            sf[1] = (floatx4){0.f, 0.f, 0.f, 0.f};
            {
                bf16x8 ka0 = *(const bf16x8*)&ks[kg2 * 32 + qi][g * 8];
                bf16x8 ka1 = *(const bf16x8*)&ks[kg2 * 32 + qi][32 + g * 8];
                floatx4 z = (floatx4){0.f, 0.f, 0.f, 0.f};
                z = __builtin_amdgcn_mfma_f32_16x16x32_bf16(ka0, qf0, z, 0, 0, 0);
                sf[0] = __builtin_amdgcn_mfma_f32_16x16x32_bf16(ka1, qf1, z, 0, 0, 0);
            }
            if (!gt) {
                bf16x8 kb0 = *(const bf16x8*)&ks[kg2 * 32 + 16 + qi][g * 8];
                bf16x8 kb1 = *(const bf16x8*)&ks[kg2 * 32 + 16 + qi][32 + g * 8];
                floatx4 z = (floatx4){0.f, 0.f, 0.f, 0.f};
                z = __builtin_amdgcn_mfma_f32_16x16x32_bf16(kb0, qf0, z, 0, 0, 0);
                sf[1] = __builtin_amdgcn_mfma_f32_16x16x32_bf16(kb1, qf1, z, 0, 0, 0);
            }
            // scores: lane holds keys kl = kg2*32 + f*16 + g*4 + r for query sq
            float p8[8];
            float mloc = -1e30f;
            #pragma unroll
            for (int f = 0; f < 2; ++f)
                #pragma unroll
                for (int r = 0; r < 4; ++r) {
                    int kl = kg2 * 32 + f * 16 + g * 4 + r;
                    bool valid;
                    if (gt) valid = (kl < 8);
                    else {
                        int kp = kbase + kl, dd = kp - sq;
                        valid = (kp >= 0) & (kp < S_LEN) & (dd <= 256) & (dd >= -256);
                    }
                    float sc = valid ? sf[f][r] * 0.125f : -1e30f;
                    p8[f * 4 + r] = sc;
                    mloc = fmaxf(mloc, sc);
                }
            mloc = fmaxf(mloc, __shfl_xor(mloc, 16));
            mloc = fmaxf(mloc, __shfl_xor(mloc, 32));
            float mnew = fmaxf(mrun, mloc);
            float alpha = __expf(mrun - mnew);
            mrun = mnew;
            float ls = 0.f;
            #pragma unroll
            for (int i = 0; i < 8; ++i) { float p = __expf(p8[i] - mnew); p8[i] = p; ls += p; }
            ls += __shfl_xor(ls, 16);
            ls += __shfl_xor(ls, 32);
            lrun = lrun * alpha + ls;
            // pack P -> wave-private LDS (row q=qi, cols f*16 + g*4 ..+3)
            u16x4 w0, w1;
            #pragma unroll
            for (int r = 0; r < 4; ++r) { w0[r] = f2bf(p8[r]); w1[r] = f2bf(p8[4 + r]); }
            *(u16x4*)&pbuf[w][qi][g * 4] = w0;
            *(u16x4*)&pbuf[w][qi][16 + g * 4] = w1;
            // rescale acc rows (row m = g*4+r, alpha lives at lane m)
            float al[4];
            #pragma unroll
            for (int r = 0; r < 4; ++r) al[r] = __shfl(alpha, g * 4 + r);
            #pragma unroll
            for (int dt = 0; dt < 4; ++dt)
                #pragma unroll
                for (int r = 0; r < 4; ++r) acc[dt][r] *= al[r];
            // P A-frag + PV MFMAs
            bf16x8 pf = *(const bf16x8*)&pbuf[w][qi][g * 8];
            #pragma unroll
            for (int dt = 0; dt < 4; ++dt) {
                bf16x8 vb = *(const bf16x8*)&vt[dt * 16 + qi][kg2 * 32 + g * 8];
                acc[dt] = __builtin_amdgcn_mfma_f32_16x16x32_bf16(pf, vb, acc[dt], 0, 0, 0);
            }
        }
    }

    float inv = 1.f / lrun;
    float li[4];
    #pragma unroll
    for (int r = 0; r < 4; ++r) li[r] = __shfl(inv, g * 4 + r);
    #pragma unroll
    for (int dt = 0; dt < 4; ++dt)
        #pragma unroll
        for (int r = 0; r < 4; ++r) {
            int s = q0w + g * 4 + r;
            aob[(size_t)s * 768 + hh * 64 + dt * 16 + qi] = f2bf(acc[dt][r] * li[r]);
        }
}

// ---------------------------------------------------------------------------
// LayerNorm helpers
// ---------------------------------------------------------------------------
#define BLOCK_MEANVAR(sum, sq, mean, inv)                                        \
    {                                                                            \
        for (int o_ = 32; o_ > 0; o_ >>= 1) {                                    \
            sum += __shfl_down(sum, o_); sq += __shfl_down(sq, o_);              \
        }                                                                        \
        __shared__ float rs_[4], rq_[4];                                         \
        if ((threadIdx.x & 63) == 0) { rs_[threadIdx.x >> 6] = sum; rq_[threadIdx.x >> 6] = sq; } \
        __syncthreads();                                                         \
        float S_ = rs_[0] + rs_[1] + rs_[2] + rs_[3];                            \
        float Q_ = rq_[0] + rq_[1] + rq_[2] + rq_[3];                            \
        mean = S_ * (1.f / 768.f);                                               \
        float var_ = Q_ * (1.f / 768.f) - mean * mean;                           \
        inv = rsqrtf(var_ + 1e-5f);                                              \
    }

__global__ __launch_bounds__(256) void embed_ln_k(
    const int* __restrict__ x, const float* __restrict__ wemb, const float* __restrict__ pemb,
    const float* __restrict__ gs, const float* __restrict__ gb,
    float* __restrict__ hf, u16* __restrict__ hb)
{
    int s = blockIdx.x, t = threadIdx.x;
    int w = s >> 9, p = s & 511;
    int id = (p == 0) ? 0 : x[w * 511 + p - 1];
    float v[3], sum = 0.f, sq = 0.f;
    #pragma unroll
    for (int r = 0; r < 3; r++) {
        int d = t + r * 256;
        float e = wemb[(size_t)id * 768 + d] + pemb[(size_t)s * 768 + d];
        v[r] = e; sum += e; sq += e * e;
    }
    float mean, inv;
    BLOCK_MEANVAR(sum, sq, mean, inv)
    #pragma unroll
    for (int r = 0; r < 3; r++) {
        int d = t + r * 256;
        float y = (v[r] - mean) * inv * gs[d] + gb[d];
        hf[(size_t)s * 768 + d] = y;
        hb[(size_t)s * 768 + d] = f2bf(y);
    }
}

__global__ __launch_bounds__(256) void ln_resid_k(
    const float* __restrict__ xa, const float* __restrict__ xb,
    const float* __restrict__ gs, const float* __restrict__ gb,
    float* __restrict__ of, u16* __restrict__ ob)
{
    int s = blockIdx.x, t = threadIdx.x;
    const float* pa = xa + (size_t)s * 768;
    const float* pb = xb + (size_t)s * 768;
    float v[3], sum = 0.f, sq = 0.f;
    #pragma unroll
    for (int r = 0; r < 3; r++) {
        int d = t + r * 256;
        float e = pa[d] + pb[d];
        v[r] = e; sum += e; sq += e * e;
    }
    float mean, inv;
    BLOCK_MEANVAR(sum, sq, mean, inv)
    #pragma unroll
    for (int r = 0; r < 3; r++) {
        int d = t + r * 256;
        float y = (v[r] - mean) * inv * gs[d] + gb[d];
        of[(size_t)s * 768 + d] = y;
        ob[(size_t)s * 768 + d] = f2bf(y);
    }
}

// ---------------------------------------------------------------------------
// Global-token attention, pass 1: split-K partials.
// grid (12 heads, 32 key-chunks of 128), 256 threads.
// qg read directly from fused projection output (bf16, scaled here).
// ---------------------------------------------------------------------------
__global__ __launch_bounds__(256) void attn_gpart_k(
    const u16* __restrict__ qkvg,
    float* __restrict__ pacc, float* __restrict__ pm, float* __restrict__ pl)
{
    const int hh = blockIdx.x, ck = blockIdx.y;
    const int t = threadIdx.x;
    __shared__ float qs[8][64];
    __shared__ __align__(16) u16 ks[128][72];   // +8 pad: stage writes c-free
    __shared__ __align__(16) u16 vs[128][64];   // read d-major -> conflict-free
    __shared__ float sc[8][128];
    __shared__ float mred[8], lred[8];

    for (int i = t; i < 512; i += 256) {
        int g = i >> 6, d = i & 63;
        qs[g][d] = bf2f(qkvg[(size_t)(g * 512) * QKVG_N + 3840 + hh * 64 + d]) * 0.125f;
    }
    const int s0 = ck * 128;
    for (int u = t; u < 1024; u += 256) {
        int r = u >> 3, c = u & 7;
        const u16* src = qkvg + (size_t)(s0 + r) * QKVG_N + hh * 64 + c * 8;
        *(uintx4*)&ks[r][c * 8] = *(const uintx4*)(src + 2304);
        *(uintx4*)&vs[r][c * 8] = *(const uintx4*)(src + 3072);
    }
    __syncthreads();

    // scores: thread (key = t&127) computes 4 queries (t>>7 selects 0-3 / 4-7)
    {
        int key = t & 127, q0 = (t >> 7) * 4;
        float a[4] = {0.f, 0.f, 0.f, 0.f};
        #pragma unroll
        for (int c = 0; c < 8; ++c) {
            uintx4 pk = *(const uintx4*)&ks[key][c * 8];
            const u16* uu = (const u16*)&pk;
            #pragma unroll
            for (int e = 0; e < 8; ++e) {
                float kv = bf2f(uu[e]);
                #pragma unroll
                for (int q = 0; q < 4; ++q) a[q] += kv * qs[q0 + q][c * 8 + e];
            }
        }
        #pragma unroll
        for (int q = 0; q < 4; ++q) sc[q0 + q][key] = a[q];
    }
    __syncthreads();

    // chunk softmax: q = t>>5, 32 lanes/query, 4 keys each
    {
        int q = t >> 5, lq = t & 31;
        float m = -1e30f;
        #pragma unroll
        for (int i = 0; i < 4; ++i) m = fmaxf(m, sc[q][lq + i * 32]);
        #pragma unroll
        for (int o = 1; o < 32; o <<= 1) m = fmaxf(m, __shfl_xor(m, o));
        float ls = 0.f;
        #pragma unroll
        for (int i = 0; i < 4; ++i) {
            float p = __expf(sc[q][lq + i * 32] - m);
            sc[q][lq + i * 32] = p; ls += p;
        }
        #pragma unroll
        for (int o = 1; o < 32; o <<= 1) ls += __shfl_xor(ls, o);
        if (lq == 0) { mred[q] = m; lred[q] = ls; }
    }
    __syncthreads();

    // partial PV: thread (d = t&63, qb = t>>6) -> o[qb][d], o[qb+4][d]
    {
        int d = t & 63, qb = t >> 6;
        float a0 = 0.f, a1 = 0.f;
        #pragma unroll 4
        for (int s = 0; s < 128; ++s) {
            float v = bf2f(vs[s][d]);
            a0 += sc[qb][s] * v;
            a1 += sc[qb + 4][s] * v;
        }
        float* pb = pacc + (((size_t)hh * 32 + ck) * 8) * 64;
        pb[qb * 64 + d] = a0;
        pb[(qb + 4) * 64 + d] = a1;
        if (t < 8) {
            pm[((size_t)hh * 32 + ck) * 8 + t] = mred[t];
            pl[((size_t)hh * 32 + ck) * 8 + t] = lred[t];
        }
    }
}

// Pass 2: merge 32 chunk partials per (head, query), overwrite GPOS rows.
__global__ __launch_bounds__(64) void attn_gred_k(
    const float* __restrict__ pacc, const float* __restrict__ pm,
    const float* __restrict__ pl, u16* __restrict__ aob)
{
    int hh = blockIdx.x, gq = blockIdx.y;
    int d = threadIdx.x;
    float M = -1e30f;
    #pragma unroll 4
    for (int c = 0; c < 32; ++c)
        M = fmaxf(M, pm[((size_t)hh * 32 + c) * 8 + gq]);
    float L = 0.f, o = 0.f;
    #pragma unroll 4
    for (int c = 0; c < 32; ++c) {
        float w = __expf(pm[((size_t)hh * 32 + c) * 8 + gq] - M);
        L += pl[((size_t)hh * 32 + c) * 8 + gq] * w;
        o += w * pacc[(((size_t)hh * 32 + c) * 8 + gq) * 64 + d];
    }
    aob[(size_t)(gq * 512) * 768 + hh * 64 + d] = f2bf(o / L);
}

__global__ __launch_bounds__(128) void head_k(
    const float* __restrict__ hf, const float* __restrict__ Wout,
    const float* __restrict__ bout, float* __restrict__ out)
{
    int g = blockIdx.x, n = threadIdx.x;
    __shared__ float hsh[768];
    for (int i = n; i < 768; i += 128) hsh[i] = hf[(size_t)(g * 512) * 768 + i];
    __syncthreads();
    float a = 0.f;
    #pragma unroll 4
    for (int k = 0; k < 768; k++) a += hsh[k] * Wout[k * 128 + n];
    out[g * 128 + n] = a + bout[n];
}

// ---------------------------------------------------------------------------
extern "C" void kernel_launch(void* const* d_in, const int* in_sizes, int n_in,
                              void* d_out, int out_size, void* d_ws, size_t ws_size,
                              hipStream_t stream)
{
    (void)in_sizes; (void)n_in; (void)out_size; (void)ws_size;
    const int*   x    = (const int*)  d_in[0];
    const float* wemb = (const float*)d_in[1];
    const float* pemb = (const float*)d_in[2];
    const float* elns = (const float*)d_in[3];
    const float* elnb = (const float*)d_in[4];
    const float* Wq   = (const float*)d_in[5];
    const float* bq   = (const float*)d_in[6];
    const float* Wk   = (const float*)d_in[7];
    const float* bk   = (const float*)d_in[8];
    const float* Wv   = (const float*)d_in[9];
    const float* bv   = (const float*)d_in[10];
    const float* Wo   = (const float*)d_in[11];
    const float* bo   = (const float*)d_in[12];
    const float* Wqg  = (const float*)d_in[13];
    const float* bqg  = (const float*)d_in[14];
    const float* Wkg  = (const float*)d_in[15];
    const float* bkg  = (const float*)d_in[16];
    const float* Wvg  = (const float*)d_in[17];
    const float* bvg  = (const float*)d_in[18];
    const float* l1s  = (const float*)d_in[19];
    const float* l1b  = (const float*)d_in[20];
    const float* W1   = (const float*)d_in[21];
    const float* b1   = (const float*)d_in[22];
    const float* W2   = (const float*)d_in[23];
    const float* b2   = (const float*)d_in[24];
    const float* l2s  = (const float*)d_in[25];
    const float* l2b  = (const float*)d_in[26];
    const float* Wout = (const float*)d_in[27];
    const float* boutp= (const float*)d_in[28];

    char* W = (char*)d_ws;
    float* hf    = (float*)(W);                  // [4096][768]  fp32
    u16*   hb    = (u16*)  (W + 12582912);       // [4096][768]  bf16
    u16*   qkvg  = (u16*)  (W + 18874368);       // [4096][4608] bf16
    u16*   vTg   = (u16*)  (W + 56623104);       // [768][4096]  bf16
    u16*   aob   = (u16*)  (W + 62914560);       // [4096][768]  bf16
    float* yf    = (float*)(W + 69206016);       // [4096][768]  fp32 (also ff2)
    u16*   ff1b  = (u16*)  (W + 81788928);       // [4096][3072] bf16
    float* bcat  = (float*)(W + 106954752);      // [4608]       fp32
    u16*   wT    = (u16*)  (W + 106973184);      // bf16 transposed weights
    u16* wqkvgT = wT;                            // [4608][768]
    u16* woT    = wT + 3538944;                  // [768][768]
    u16* w1T    = wT + 4128768;                  // [3072][768]
    u16* w2T    = wT + 6488064;                  // [768][3072]
    float* pacc = (float*)(W + 124667904);       // [12][32][8][64] fp32
    float* pmw  = (float*)(W + 125454336);       // [12][32][8]     fp32
    float* plw  = (float*)(W + 125466624);       // [12][32][8]     fp32

    embed_ln_k<<<4096, 256, 0, stream>>>(x, wemb, pemb, elns, elnb, hf, hb);

    for (int l = 0; l < NL; ++l) {
        const float* Wq_l  = Wq  + (size_t)l * 768 * 768;
        const float* Wk_l  = Wk  + (size_t)l * 768 * 768;
        const float* Wv_l  = Wv  + (size_t)l * 768 * 768;
        const float* Wo_l  = Wo  + (size_t)l * 768 * 768;
        const float* Wqg_l = Wqg + (size_t)l * 768 * 768;
        const float* Wkg_l = Wkg + (size_t)l * 768 * 768;
        const float* Wvg_l = Wvg + (size_t)l * 768 * 768;
        const float* W1_l  = W1  + (size_t)l * 768 * 3072;
        const float* W2_l  = W2  + (size_t)l * 3072 * 768;
        const float* bq_l  = bq  + (size_t)l * 768;
        const float* bk_l  = bk  + (size_t)l * 768;
        const float* bv_l  = bv  + (size_t)l * 768;
        const float* bo_l  = bo  + (size_t)l * 768;
        const float* bqg_l = bqg + (size_t)l * 768;
        const float* bkg_l = bkg + (size_t)l * 768;
        const float* bvg_l = bvg + (size_t)l * 768;
        const float* b1_l  = b1  + (size_t)l * 3072;
        const float* b2_l  = b2  + (size_t)l * 768;
        const float* l1s_l = l1s + (size_t)l * 768;
        const float* l1b_l = l1b + (size_t)l * 768;
        const float* l2s_l = l2s + (size_t)l * 768;
        const float* l2b_l = l2b + (size_t)l * 768;

        prep_weights_k<<<8658, 256, 0, stream>>>(
            Wq_l, Wk_l, Wv_l, Wkg_l, Wvg_l, Wqg_l, Wo_l, W1_l, W2_l,
            bq_l, bk_l, bv_l, bkg_l, bvg_l, bqg_l,
            wqkvgT, woT, w1T, w2T, bcat);

        // fused q/k/v/kg/vg/qg projection -> bf16 [4096][4608]
        gemm_k<0, 0, 1, 1><<<dim3(32, 36), 256, 0, stream>>>(
            hb, wqkvgT, bcat, (float*)nullptr, qkvg, QKVG_N, 768);

        vtrans_k<<<dim3(64, 12), 256, 0, stream>>>(qkvg, vTg);

        attn_local_k<<<dim3(12, 64), 256, 0, stream>>>(qkvg, vTg, aob);

        attn_gpart_k<<<dim3(12, 32), 256, 0, stream>>>(qkvg, pacc, pmw, plw);
        attn_gred_k<<<dim3(12, 8), 64, 0, stream>>>(pacc, pmw, plw, aob);

        gemm_k<0, 1, 0, 0><<<dim3(32, 6), 256, 0, stream>>>(
            aob, woT, bo_l, yf, (u16*)nullptr, 768, 768);
        ln_resid_k<<<4096, 256, 0, stream>>>(hf, yf, l1s_l, l1b_l, hf, hb);

        gemm_k<1, 0, 1, 0><<<dim3(32, 24), 256, 0, stream>>>(
            hb, w1T, b1_l, (float*)nullptr, ff1b, 3072, 768);
        gemm_k<0, 1, 0, 0><<<dim3(32, 6), 256, 0, stream>>>(
            ff1b, w2T, b2_l, yf, (u16*)nullptr, 768, 3072);
        ln_resid_k<<<4096, 256, 0, stream>>>(hf, yf, l2s_l, l2b_l, hf, hb);
    }

    head_k<<<8, 128, 0, stream>>>(hf, Wout, boutp, (float*)d_out);
}

// Round 3
// 3101.727 us; speedup vs baseline: 1.8450x; 1.0339x over previous
//
#include <hip/hip_runtime.h>
#include <hip/hip_bf16.h>

// ---------------------------------------------------------------------------
// Longformer forward, MI355X. Round 4: XCD-bijective block swizzle on GEMMs
// and local attention, split-K for the under-gridded N=768 GEMMs (partials
// reduced for free inside ln_resid), vtrans fused into the proj GEMM
// epilogue, and all 12 layers' weight prep batched into one upfront launch.
// Constants: B=1 NW=8 SEG=511 S=4096 W=256 C=16 H=12 D=64 DM=768 FF=3072 L=12
// ---------------------------------------------------------------------------

typedef unsigned short u16;
typedef __attribute__((ext_vector_type(4))) float floatx4;
typedef __attribute__((ext_vector_type(4))) unsigned int uintx4;
typedef __attribute__((ext_vector_type(8))) short bf16x8;
typedef __attribute__((ext_vector_type(4))) u16 u16x4;

#define S_LEN 4096
#define QKVG_N 4608   // q(0) k(768) v(1536) kg(2304) vg(3072) qg(3840)
#define NL 12

__device__ inline u16 f2bf(float x) {
    union { __hip_bfloat16 b; u16 u; } cv;
    cv.b = __float2bfloat16(x);
    return cv.u;
}
__device__ inline float bf2f(u16 u) {
    union { float f; unsigned int i; } c; c.i = ((unsigned int)u) << 16; return c.f;
}
__device__ inline float gelu_f(float x) {
    float x3 = x * x * x;
    return 0.5f * x * (1.0f + tanhf(0.7978845608028654f * (x + 0.044715f * x3)));
}

#define GLDS16(g, l)                                                              \
    __builtin_amdgcn_global_load_lds(                                             \
        (const __attribute__((address_space(1))) unsigned int*)(g),               \
        (__attribute__((address_space(3))) unsigned int*)(l), 16, 0, 0)

// ---------------------------------------------------------------------------
// Weight prep, ALL layers in one launch: fp32 [K][N] -> bf16 [N][K] + bias
// concat. blockIdx.y = layer. Per-layer wT block: qkvg(3538944) wo(589824)
// w1(2359296) w2(2359296) u16 = 8847360 u16 stride.
// ---------------------------------------------------------------------------
__global__ __launch_bounds__(256) void prep_weights_k(
    const float* __restrict__ Wq0, const float* __restrict__ Wk0, const float* __restrict__ Wv0,
    const float* __restrict__ Wkg0, const float* __restrict__ Wvg0, const float* __restrict__ Wqg0,
    const float* __restrict__ Wo0, const float* __restrict__ W10, const float* __restrict__ W20,
    const float* __restrict__ bq0, const float* __restrict__ bk0, const float* __restrict__ bv0,
    const float* __restrict__ bkg0, const float* __restrict__ bvg0, const float* __restrict__ bqg0,
    u16* __restrict__ wTall, float* __restrict__ bcatall)
{
    const int l = blockIdx.y;
    const size_t sqo = (size_t)l * 589824;     // 768*768 fp32 stride
    const size_t sff = (size_t)l * 2359296;    // 768*3072 fp32 stride
    u16* wqkvgT = wTall + (size_t)l * 8847360;
    u16* woT = wqkvgT + 3538944;
    u16* w1T = woT + 589824;
    u16* w2T = w1T + 2359296;
    float* bcat = bcatall + (size_t)l * 4608;

    int bid = blockIdx.x;
    int t = threadIdx.x;
    if (bid >= 8640) {                       // bias concat tail: 4608 floats
        int i = (bid - 8640) * 256 + t;
        float v;
        if (i < 768)       v = bq0[l * 768 + i];
        else if (i < 1536) v = bk0[l * 768 + i - 768];
        else if (i < 2304) v = bv0[l * 768 + i - 1536];
        else if (i < 3072) v = bkg0[l * 768 + i - 2304];
        else if (i < 3840) v = bvg0[l * 768 + i - 3072];
        else               v = bqg0[l * 768 + i - 3840];
        bcat[i] = v;
        return;
    }
    const float* src; u16* dst; int K, N, tile;
    if (bid < 3456) {
        int m = bid / 576; tile = bid % 576;
        src = ((m == 0) ? Wq0 : (m == 1) ? Wk0 : (m == 2) ? Wv0 :
               (m == 3) ? Wkg0 : (m == 4) ? Wvg0 : Wqg0) + sqo;
        dst = wqkvgT + (size_t)m * 589824;
        K = 768; N = 768;
    } else if (bid < 4032) { tile = bid - 3456; src = Wo0 + sqo; dst = woT; K = 768; N = 768; }
    else if (bid < 6336)   { tile = bid - 4032; src = W10 + sff; dst = w1T; K = 768; N = 3072; }
    else                   { tile = bid - 6336; src = W20 + sff; dst = w2T; K = 3072; N = 768; }

    int nt = N >> 5;
    int k0 = (tile / nt) << 5, n0 = (tile % nt) << 5;
    __shared__ float tb[32][33];
    int tx = t & 31, ty = t >> 5;            // ty: 0..7
    #pragma unroll
    for (int r = 0; r < 4; r++)
        tb[ty + r * 8][tx] = src[(size_t)(k0 + ty + r * 8) * N + n0 + tx];
    __syncthreads();
    #pragma unroll
    for (int r = 0; r < 4; r++) {
        int nn = ty + r * 8;
        dst[(size_t)(n0 + nn) * K + k0 + tx] = f2bf(tb[tx][nn]);
    }
}

// ---------------------------------------------------------------------------
// bf16 MFMA GEMM with global_load_lds staging (m97 pattern).
// - XCD-bijective swizzle on the flattened (x,y) grid (gridDim.x == 32,
//   nwg per z-slice % 8 == 0 for all call sites).
// - SKIPQG: qg N-tiles (by>=30) only needed where bm%512==0.
// - WVT: v-column tiles (cc in [1536,2304)) also write transposed vTg.
// - SPLITB: blockIdx.z = K-split index; A/B offset by z*K; C slab per z;
//   bias added only by z==0 (partials summed later in ln_resid).
// ---------------------------------------------------------------------------
template <int ACT, int WF, int WB, int SKIPQG, int WVT, int SPLITB>
__global__ __launch_bounds__(256) void gemm_k(
    const u16* __restrict__ A, const u16* __restrict__ Bt,
    const float* __restrict__ bias,
    float* __restrict__ Cf, u16* __restrict__ Cb, u16* __restrict__ vTg,
    int N, int K, int lda, int ldb)
{
    // XCD-bijective swizzle (nwg % 8 == 0 at every call site)
    int lin = blockIdx.y * 32 + blockIdx.x;
    int qq = gridDim.y << 2;                   // nwg/8 = 32*gy/8
    int wg = (lin & 7) * qq + (lin >> 3);
    int bx = wg & 31, by = wg >> 5;
    if (SKIPQG && by >= 30 && (bx & 3) != 0) return;
    int bm = bx * 128, bn = by * 128;
    const int zoff = SPLITB ? blockIdx.z : 0;
    const u16* Ab = A + (size_t)zoff * K;
    const u16* Bb = Bt + (size_t)zoff * K;
    float* Cfz = WF ? Cf + (size_t)zoff * S_LEN * N : (float*)nullptr;

    __shared__ __align__(16) u16 As[128][32];
    __shared__ __align__(16) u16 Bs[128][32];
    int t = threadIdx.x, lane = t & 63, wv = t >> 6;
    int wm = (wv >> 1) * 64, wn = (wv & 1) * 64;
    int arow = t >> 2, acol = (t & 3) * 8;     // staging: 64 rows x (4x8 bf16)
    int fr = lane & 15, fo = (lane >> 4) * 8;  // fragment row / k-offset

    floatx4 acc[4][4];
    #pragma unroll
    for (int i = 0; i < 4; i++)
        #pragma unroll
        for (int j = 0; j < 4; j++) acc[i][j] = (floatx4){0.f, 0.f, 0.f, 0.f};

    const int nk = K >> 5;
    for (int kt = 0; kt < nk; ++kt) {
        const u16* ag = Ab + (size_t)(bm + arow) * lda + kt * 32 + acol;
        const u16* bg = Bb + (size_t)(bn + arow) * ldb + kt * 32 + acol;
        GLDS16(ag,                     &As[arow][acol]);
        GLDS16(ag + (size_t)64 * lda,  &As[arow + 64][acol]);
        GLDS16(bg,                     &Bs[arow][acol]);
        GLDS16(bg + (size_t)64 * ldb,  &Bs[arow + 64][acol]);
        __syncthreads();
        bf16x8 af[4], bfr[4];
        #pragma unroll
        for (int i = 0; i < 4; i++) af[i]  = *(const bf16x8*)&As[wm + i * 16 + fr][fo];
        #pragma unroll
        for (int i = 0; i < 4; i++) bfr[i] = *(const bf16x8*)&Bs[wn + i * 16 + fr][fo];
        #pragma unroll
        for (int i = 0; i < 4; i++)
            #pragma unroll
            for (int j = 0; j < 4; j++)
                acc[i][j] = __builtin_amdgcn_mfma_f32_16x16x32_bf16(af[i], bfr[j], acc[i][j], 0, 0, 0);
        __syncthreads();
    }

    int dr = (lane >> 4) * 4, dc = lane & 15;
    #pragma unroll
    for (int i = 0; i < 4; i++) {
        #pragma unroll
        for (int j = 0; j < 4; j++) {
            int r0 = bm + wm + i * 16 + dr;
            int cc = bn + wn + j * 16 + dc;
            float bsv = (!SPLITB || blockIdx.z == 0) ? bias[cc] : 0.f;
            u16x4 tv;
            #pragma unroll
            for (int r = 0; r < 4; r++) {
                float v = acc[i][j][r] + bsv;
                if (ACT == 1) v = gelu_f(v);
                if (WF) Cfz[(size_t)(r0 + r) * N + cc] = v;
                if (WB) { u16 b = f2bf(v); Cb[(size_t)(r0 + r) * N + cc] = b; tv[r] = b; }
            }
            if (WVT && cc >= 1536 && cc < 2304)
                *(u16x4*)&vTg[(size_t)(cc - 1536) * 4096 + r0] = tv;
        }
    }
}

// ---------------------------------------------------------------------------
// MFMA local banded attention + joint softmax with 8 global CLS keys.
// grid (64 q-tiles, 12 heads) with XCD swizzle so each XCD works ~1.5 heads
// (K/V band L2-resident). 4 waves x 16 queries; computes S^T via mfma(K, Q);
// PV uses pre-transposed V (vTg). Tile 0 = 8 global CLS keys.
// ---------------------------------------------------------------------------
__global__ __launch_bounds__(256) void attn_local_k(
    const u16* __restrict__ qkvg, const u16* __restrict__ vTg, u16* __restrict__ aob)
{
    int lin = blockIdx.y * 64 + blockIdx.x;   // nwg = 768
    int wg = (lin & 7) * 96 + (lin >> 3);
    const int qb = wg & 63, hh = wg >> 6;
    const int t = threadIdx.x, lane = t & 63, w = t >> 6;
    const int g = lane >> 4, qi = lane & 15;
    __shared__ __align__(16) u16 ks[64][72];
    __shared__ __align__(16) u16 vt[64][72];
    __shared__ __align__(16) u16 pbuf[4][16][40];

    const int q0w = qb * 64 + w * 16;
    const int sq = q0w + qi;                 // softmax-column query (per lane)

    bf16x8 qf0, qf1;                          // Q B-operand frags (2 k-steps)
    {
        const u16* qp = qkvg + (size_t)(q0w + qi) * QKVG_N + hh * 64 + g * 8;
        qf0 = *(const bf16x8*)qp;
        qf1 = *(const bf16x8*)(qp + 32);
    }

    floatx4 acc[4];
    #pragma unroll
    for (int i = 0; i < 4; i++) acc[i] = (floatx4){0.f, 0.f, 0.f, 0.f};
    float mrun = -1e30f, lrun = 0.f;

    for (int tile = 0; tile <= 9; ++tile) {
        const int kbase = qb * 64 - 256 + (tile - 1) * 64;
        if (tile > 0 && (kbase < -63 || kbase >= S_LEN)) continue;  // uniform skip
        __syncthreads();
        if (tile == 0) {
            // zero vt (avoid NaN junk x P=0), then fill 8 global K/V columns
            for (int i = t; i < 576; i += 256) ((uintx4*)vt)[i] = (uintx4){0, 0, 0, 0};
            __syncthreads();
            if (t < 64) {
                int gg = t >> 3, d0 = (t & 7) * 8;
                *(uintx4*)&ks[gg][d0] =
                    *(const uintx4*)(qkvg + (size_t)(gg * 512) * QKVG_N + 768 + hh * 64 + d0);
            }
            for (int e = t; e < 512; e += 256) {
                int d = e >> 3, gg = e & 7;
                vt[d][gg] = vTg[(size_t)(hh * 64 + d) * 4096 + gg * 512];
            }
        } else {
            for (int c = t; c < 512; c += 256) {
                int r = c >> 3, c0 = (c & 7) * 8;
                int row = kbase + r; row = row < 0 ? 0 : (row > 4095 ? 4095 : row);
                *(uintx4*)&ks[r][c0] =
                    *(const uintx4*)(qkvg + (size_t)row * QKVG_N + 768 + hh * 64 + c0);
                int gc = kbase + c0; gc = gc < 0 ? 0 : (gc > 4088 ? 4088 : gc);
                *(uintx4*)&vt[r][c0] =
                    *(const uintx4*)(vTg + (size_t)(hh * 64 + r) * 4096 + gc);
            }
        }
        __syncthreads();

        const bool gt = (tile == 0);
        const int ng = gt ? 1 : 2;
        for (int kg2 = 0; kg2 < ng; ++kg2) {
            floatx4 sf[2];
            sf[1] = (floatx4){0.f, 0.f, 0.f, 0.f};
            {
                bf16x8 ka0 = *(const bf16x8*)&ks[kg2 * 32 + qi][g * 8];
                bf16x8 ka1 = *(const bf16x8*)&ks[kg2 * 32 + qi][32 + g * 8];
                floatx4 z = (floatx4){0.f, 0.f, 0.f, 0.f};
                z = __builtin_amdgcn_mfma_f32_16x16x32_bf16(ka0, qf0, z, 0, 0, 0);
                sf[0] = __builtin_amdgcn_mfma_f32_16x16x32_bf16(ka1, qf1, z, 0, 0, 0);
            }
            if (!gt) {
                bf16x8 kb0 = *(const bf16x8*)&ks[kg2 * 32 + 16 + qi][g * 8];
                bf16x8 kb1 = *(const bf16x8*)&ks[kg2 * 32 + 16 + qi][32 + g * 8];
                floatx4 z = (floatx4){0.f, 0.f, 0.f, 0.f};
                z = __builtin_amdgcn_mfma_f32_16x16x32_bf16(kb0, qf0, z, 0, 0, 0);
                sf[1] = __builtin_amdgcn_mfma_f32_16x16x32_bf16(kb1, qf1, z, 0, 0, 0);
            }
            // scores: lane holds keys kl = kg2*32 + f*16 + g*4 + r for query sq
            float p8[8];
            float mloc = -1e30f;
            #pragma unroll
            for (int f = 0; f < 2; ++f)
                #pragma unroll
                for (int r = 0; r < 4; ++r) {
                    int kl = kg2 * 32 + f * 16 + g * 4 + r;
                    bool valid;
                    if (gt) valid = (kl < 8);
                    else {
                        int kp = kbase + kl, dd = kp - sq;
                        valid = (kp >= 0) & (kp < S_LEN) & (dd <= 256) & (dd >= -256);
                    }
                    float sc = valid ? sf[f][r] * 0.125f : -1e30f;
                    p8[f * 4 + r] = sc;
                    mloc = fmaxf(mloc, sc);
                }
            mloc = fmaxf(mloc, __shfl_xor(mloc, 16));
            mloc = fmaxf(mloc, __shfl_xor(mloc, 32));
            float mnew = fmaxf(mrun, mloc);
            float alpha = __expf(mrun - mnew);
            mrun = mnew;
            float ls = 0.f;
            #pragma unroll
            for (int i = 0; i < 8; ++i) { float p = __expf(p8[i] - mnew); p8[i] = p; ls += p; }
            ls += __shfl_xor(ls, 16);
            ls += __shfl_xor(ls, 32);
            lrun = lrun * alpha + ls;
            // pack P -> wave-private LDS (row q=qi, cols f*16 + g*4 ..+3)
            u16x4 w0, w1;
            #pragma unroll
            for (int r = 0; r < 4; ++r) { w0[r] = f2bf(p8[r]); w1[r] = f2bf(p8[4 + r]); }
            *(u16x4*)&pbuf[w][qi][g * 4] = w0;
            *(u16x4*)&pbuf[w][qi][16 + g * 4] = w1;
            // rescale acc rows (row m = g*4+r, alpha lives at lane m)
            float al[4];
            #pragma unroll
            for (int r = 0; r < 4; ++r) al[r] = __shfl(alpha, g * 4 + r);
            #pragma unroll
            for (int dt = 0; dt < 4; ++dt)
                #pragma unroll
                for (int r = 0; r < 4; ++r) acc[dt][r] *= al[r];
            // P A-frag + PV MFMAs
            bf16x8 pf = *(const bf16x8*)&pbuf[w][qi][g * 8];
            #pragma unroll
            for (int dt = 0; dt < 4; ++dt) {
                bf16x8 vb = *(const bf16x8*)&vt[dt * 16 + qi][kg2 * 32 + g * 8];
                acc[dt] = __builtin_amdgcn_mfma_f32_16x16x32_bf16(pf, vb, acc[dt], 0, 0, 0);
            }
        }
    }

    float inv = 1.f / lrun;
    float li[4];
    #pragma unroll
    for (int r = 0; r < 4; ++r) li[r] = __shfl(inv, g * 4 + r);
    #pragma unroll
    for (int dt = 0; dt < 4; ++dt)
        #pragma unroll
        for (int r = 0; r < 4; ++r) {
            int s = q0w + g * 4 + r;
            aob[(size_t)s * 768 + hh * 64 + dt * 16 + qi] = f2bf(acc[dt][r] * li[r]);
        }
}

// ---------------------------------------------------------------------------
// LayerNorm helpers
// ---------------------------------------------------------------------------
#define BLOCK_MEANVAR(sum, sq, mean, inv)                                        \
    {                                                                            \
        for (int o_ = 32; o_ > 0; o_ >>= 1) {                                    \
            sum += __shfl_down(sum, o_); sq += __shfl_down(sq, o_);              \
        }                                                                        \
        __shared__ float rs_[4], rq_[4];                                         \
        if ((threadIdx.x & 63) == 0) { rs_[threadIdx.x >> 6] = sum; rq_[threadIdx.x >> 6] = sq; } \
        __syncthreads();                                                         \
        float S_ = rs_[0] + rs_[1] + rs_[2] + rs_[3];                            \
        float Q_ = rq_[0] + rq_[1] + rq_[2] + rq_[3];                            \
        mean = S_ * (1.f / 768.f);                                               \
        float var_ = Q_ * (1.f / 768.f) - mean * mean;                           \
        inv = rsqrtf(var_ + 1e-5f);                                              \
    }

__global__ __launch_bounds__(256) void embed_ln_k(
    const int* __restrict__ x, const float* __restrict__ wemb, const float* __restrict__ pemb,
    const float* __restrict__ gs, const float* __restrict__ gb,
    float* __restrict__ hf, u16* __restrict__ hb)
{
    int s = blockIdx.x, t = threadIdx.x;
    int w = s >> 9, p = s & 511;
    int id = (p == 0) ? 0 : x[w * 511 + p - 1];
    float v[3], sum = 0.f, sq = 0.f;
    #pragma unroll
    for (int r = 0; r < 3; r++) {
        int d = t + r * 256;
        float e = wemb[(size_t)id * 768 + d] + pemb[(size_t)s * 768 + d];
        v[r] = e; sum += e; sq += e * e;
    }
    float mean, inv;
    BLOCK_MEANVAR(sum, sq, mean, inv)
    #pragma unroll
    for (int r = 0; r < 3; r++) {
        int d = t + r * 256;
        float y = (v[r] - mean) * inv * gs[d] + gb[d];
        hf[(size_t)s * 768 + d] = y;
        hb[(size_t)s * 768 + d] = f2bf(y);
    }
}

// of = LN(xa + xb + xc): xb/xc are the two split-K GEMM partial outputs.
__global__ __launch_bounds__(256) void ln_resid_k(
    const float* __restrict__ xa, const float* __restrict__ xb, const float* __restrict__ xc,
    const float* __restrict__ gs, const float* __restrict__ gb,
    float* __restrict__ of, u16* __restrict__ ob)
{
    int s = blockIdx.x, t = threadIdx.x;
    const float* pa = xa + (size_t)s * 768;
    const float* pb = xb + (size_t)s * 768;
    const float* pc = xc + (size_t)s * 768;
    float v[3], sum = 0.f, sq = 0.f;
    #pragma unroll
    for (int r = 0; r < 3; r++) {
        int d = t + r * 256;
        float e = pa[d] + pb[d] + pc[d];
        v[r] = e; sum += e; sq += e * e;
    }
    float mean, inv;
    BLOCK_MEANVAR(sum, sq, mean, inv)
    #pragma unroll
    for (int r = 0; r < 3; r++) {
        int d = t + r * 256;
        float y = (v[r] - mean) * inv * gs[d] + gb[d];
        of[(size_t)s * 768 + d] = y;
        ob[(size_t)s * 768 + d] = f2bf(y);
    }
}

// ---------------------------------------------------------------------------
// Global-token attention, pass 1: split-K partials.
// grid (12 heads, 32 key-chunks of 128), 256 threads.
// qg read directly from fused projection output (bf16, scaled here).
// ---------------------------------------------------------------------------
__global__ __launch_bounds__(256) void attn_gpart_k(
    const u16* __restrict__ qkvg,
    float* __restrict__ pacc, float* __restrict__ pm, float* __restrict__ pl)
{
    const int hh = blockIdx.x, ck = blockIdx.y;
    const int t = threadIdx.x;
    __shared__ float qs[8][64];
    __shared__ __align__(16) u16 ks[128][72];   // +8 pad: stage writes c-free
    __shared__ __align__(16) u16 vs[128][64];   // read d-major -> conflict-free
    __shared__ float sc[8][128];
    __shared__ float mred[8], lred[8];

    for (int i = t; i < 512; i += 256) {
        int g = i >> 6, d = i & 63;
        qs[g][d] = bf2f(qkvg[(size_t)(g * 512) * QKVG_N + 3840 + hh * 64 + d]) * 0.125f;
    }
    const int s0 = ck * 128;
    for (int u = t; u < 1024; u += 256) {
        int r = u >> 3, c = u & 7;
        const u16* src = qkvg + (size_t)(s0 + r) * QKVG_N + hh * 64 + c * 8;
        *(uintx4*)&ks[r][c * 8] = *(const uintx4*)(src + 2304);
        *(uintx4*)&vs[r][c * 8] = *(const uintx4*)(src + 3072);
    }
    __syncthreads();

    // scores: thread (key = t&127) computes 4 queries (t>>7 selects 0-3 / 4-7)
    {
        int key = t & 127, q0 = (t >> 7) * 4;
        float a[4] = {0.f, 0.f, 0.f, 0.f};
        #pragma unroll
        for (int c = 0; c < 8; ++c) {
            uintx4 pk = *(const uintx4*)&ks[key][c * 8];
            const u16* uu = (const u16*)&pk;
            #pragma unroll
            for (int e = 0; e < 8; ++e) {
                float kv = bf2f(uu[e]);
                #pragma unroll
                for (int q = 0; q < 4; ++q) a[q] += kv * qs[q0 + q][c * 8 + e];
            }
        }
        #pragma unroll
        for (int q = 0; q < 4; ++q) sc[q0 + q][key] = a[q];
    }
    __syncthreads();

    // chunk softmax: q = t>>5, 32 lanes/query, 4 keys each
    {
        int q = t >> 5, lq = t & 31;
        float m = -1e30f;
        #pragma unroll
        for (int i = 0; i < 4; ++i) m = fmaxf(m, sc[q][lq + i * 32]);
        #pragma unroll
        for (int o = 1; o < 32; o <<= 1) m = fmaxf(m, __shfl_xor(m, o));
        float ls = 0.f;
        #pragma unroll
        for (int i = 0; i < 4; ++i) {
            float p = __expf(sc[q][lq + i * 32] - m);
            sc[q][lq + i * 32] = p; ls += p;
        }
        #pragma unroll
        for (int o = 1; o < 32; o <<= 1) ls += __shfl_xor(ls, o);
        if (lq == 0) { mred[q] = m; lred[q] = ls; }
    }
    __syncthreads();

    // partial PV: thread (d = t&63, qb = t>>6) -> o[qb][d], o[qb+4][d]
    {
        int d = t & 63, qb = t >> 6;
        float a0 = 0.f, a1 = 0.f;
        #pragma unroll 4
        for (int s = 0; s < 128; ++s) {
            float v = bf2f(vs[s][d]);
            a0 += sc[qb][s] * v;
            a1 += sc[qb + 4][s] * v;
        }
        float* pb = pacc + (((size_t)hh * 32 + ck) * 8) * 64;
        pb[qb * 64 + d] = a0;
        pb[(qb + 4) * 64 + d] = a1;
        if (t < 8) {
            pm[((size_t)hh * 32 + ck) * 8 + t] = mred[t];
            pl[((size_t)hh * 32 + ck) * 8 + t] = lred[t];
        }
    }
}

// Pass 2: merge 32 chunk partials per (head, query), overwrite GPOS rows.
__global__ __launch_bounds__(64) void attn_gred_k(
    const float* __restrict__ pacc, const float* __restrict__ pm,
    const float* __restrict__ pl, u16* __restrict__ aob)
{
    int hh = blockIdx.x, gq = blockIdx.y;
    int d = threadIdx.x;
    float M = -1e30f;
    #pragma unroll 4
    for (int c = 0; c < 32; ++c)
        M = fmaxf(M, pm[((size_t)hh * 32 + c) * 8 + gq]);
    float L = 0.f, o = 0.f;
    #pragma unroll 4
    for (int c = 0; c < 32; ++c) {
        float w = __expf(pm[((size_t)hh * 32 + c) * 8 + gq] - M);
        L += pl[((size_t)hh * 32 + c) * 8 + gq] * w;
        o += w * pacc[(((size_t)hh * 32 + c) * 8 + gq) * 64 + d];
    }
    aob[(size_t)(gq * 512) * 768 + hh * 64 + d] = f2bf(o / L);
}

__global__ __launch_bounds__(128) void head_k(
    const float* __restrict__ hf, const float* __restrict__ Wout,
    const float* __restrict__ bout, float* __restrict__ out)
{
    int g = blockIdx.x, n = threadIdx.x;
    __shared__ float hsh[768];
    for (int i = n; i < 768; i += 128) hsh[i] = hf[(size_t)(g * 512) * 768 + i];
    __syncthreads();
    float a = 0.f;
    #pragma unroll 4
    for (int k = 0; k < 768; k++) a += hsh[k] * Wout[k * 128 + n];
    out[g * 128 + n] = a + bout[n];
}

// ---------------------------------------------------------------------------
extern "C" void kernel_launch(void* const* d_in, const int* in_sizes, int n_in,
                              void* d_out, int out_size, void* d_ws, size_t ws_size,
                              hipStream_t stream)
{
    (void)in_sizes; (void)n_in; (void)out_size; (void)ws_size;
    const int*   x    = (const int*)  d_in[0];
    const float* wemb = (const float*)d_in[1];
    const float* pemb = (const float*)d_in[2];
    const float* elns = (const float*)d_in[3];
    const float* elnb = (const float*)d_in[4];
    const float* Wq   = (const float*)d_in[5];
    const float* bq   = (const float*)d_in[6];
    const float* Wk   = (const float*)d_in[7];
    const float* bk   = (const float*)d_in[8];
    const float* Wv   = (const float*)d_in[9];
    const float* bv   = (const float*)d_in[10];
    const float* Wo   = (const float*)d_in[11];
    const float* bo   = (const float*)d_in[12];
    const float* Wqg  = (const float*)d_in[13];
    const float* bqg  = (const float*)d_in[14];
    const float* Wkg  = (const float*)d_in[15];
    const float* bkg  = (const float*)d_in[16];
    const float* Wvg  = (const float*)d_in[17];
    const float* bvg  = (const float*)d_in[18];
    const float* l1s  = (const float*)d_in[19];
    const float* l1b  = (const float*)d_in[20];
    const float* W1   = (const float*)d_in[21];
    const float* b1   = (const float*)d_in[22];
    const float* W2   = (const float*)d_in[23];
    const float* b2   = (const float*)d_in[24];
    const float* l2s  = (const float*)d_in[25];
    const float* l2b  = (const float*)d_in[26];
    const float* Wout = (const float*)d_in[27];
    const float* boutp= (const float*)d_in[28];

    char* W = (char*)d_ws;
    float* hf    = (float*)(W);                  // [4096][768]  fp32
    u16*   hb    = (u16*)  (W + 12582912);       // [4096][768]  bf16
    u16*   qkvg  = (u16*)  (W + 18874368);       // [4096][4608] bf16
    u16*   vTg   = (u16*)  (W + 56623104);       // [768][4096]  bf16
    u16*   aob   = (u16*)  (W + 62914560);       // [4096][768]  bf16
    float* yf    = (float*)(W + 69206016);       // [2][4096][768] fp32 split slabs
    u16*   ff1b  = (u16*)  (W + 94371840);       // [4096][3072] bf16
    float* pacc  = (float*)(W + 119537664);      // [12][32][8][64] fp32
    float* pmw   = (float*)(W + 120324096);      // [12][32][8]     fp32
    float* plw   = (float*)(W + 120336384);      // [12][32][8]     fp32
    float* bcatall = (float*)(W + 120348672);    // [12][4608]      fp32
    u16*   wTall = (u16*)  (W + 120569856);      // [12] x 8847360 u16

    // All-layer weight prep (one launch)
    prep_weights_k<<<dim3(8658, 12), 256, 0, stream>>>(
        Wq, Wk, Wv, Wkg, Wvg, Wqg, Wo, W1, W2,
        bq, bk, bv, bkg, bvg, bqg, wTall, bcatall);

    embed_ln_k<<<4096, 256, 0, stream>>>(x, wemb, pemb, elns, elnb, hf, hb);

    float* yf0 = yf;
    float* yf1 = yf + (size_t)4096 * 768;

    for (int l = 0; l < NL; ++l) {
        u16* wTl      = wTall + (size_t)l * 8847360;
        u16* wqkvgT_l = wTl;
        u16* woT_l    = wTl + 3538944;
        u16* w1T_l    = woT_l + 589824;
        u16* w2T_l    = w1T_l + 2359296;
        float* bcat_l = bcatall + (size_t)l * 4608;
        const float* bo_l  = bo  + (size_t)l * 768;
        const float* b1_l  = b1  + (size_t)l * 3072;
        const float* b2_l  = b2  + (size_t)l * 768;
        const float* l1s_l = l1s + (size_t)l * 768;
        const float* l1b_l = l1b + (size_t)l * 768;
        const float* l2s_l = l2s + (size_t)l * 768;
        const float* l2b_l = l2b + (size_t)l * 768;

        // fused q/k/v/kg/vg/qg projection -> bf16 [4096][4608] (+ vTg fused)
        gemm_k<0, 0, 1, 1, 1, 0><<<dim3(32, 36), 256, 0, stream>>>(
            hb, wqkvgT_l, bcat_l, (float*)nullptr, qkvg, vTg, QKVG_N, 768, 768, 768);

        attn_local_k<<<dim3(64, 12), 256, 0, stream>>>(qkvg, vTg, aob);

        attn_gpart_k<<<dim3(12, 32), 256, 0, stream>>>(qkvg, pacc, pmw, plw);
        attn_gred_k<<<dim3(12, 8), 64, 0, stream>>>(pacc, pmw, plw, aob);

        // attention output proj, split-K x2 (K=384 each)
        gemm_k<0, 1, 0, 0, 0, 1><<<dim3(32, 6, 2), 256, 0, stream>>>(
            aob, woT_l, bo_l, yf, (u16*)nullptr, (u16*)nullptr, 768, 384, 768, 768);
        ln_resid_k<<<4096, 256, 0, stream>>>(hf, yf0, yf1, l1s_l, l1b_l, hf, hb);

        gemm_k<1, 0, 1, 0, 0, 0><<<dim3(32, 24), 256, 0, stream>>>(
            hb, w1T_l, b1_l, (float*)nullptr, ff1b, (u16*)nullptr, 3072, 768, 768, 768);
        // FFN down proj, split-K x2 (K=1536 each)
        gemm_k<0, 1, 0, 0, 0, 1><<<dim3(32, 6, 2), 256, 0, stream>>>(
            ff1b, w2T_l, b2_l, yf, (u16*)nullptr, (u16*)nullptr, 768, 1536, 3072, 3072);
        ln_resid_k<<<4096, 256, 0, stream>>>(hf, yf0, yf1, l2s_l, l2b_l, hf, hb);
    }

    head_k<<<8, 128, 0, stream>>>(hf, Wout, boutp, (float*)d_out);
}

// Round 4
// 2900.020 us; speedup vs baseline: 1.9733x; 1.0696x over previous
//
#include <hip/hip_runtime.h>
#include <hip/hip_bf16.h>

// ---------------------------------------------------------------------------
// Longformer forward, MI355X. Round 5: prep_weights v2 (64x64 tiles, f4 reads,
// u16x4 coalesced writes), GEMM BK=64 (half the barrier drains), attn_local
// dead-clamp/mask elision (only band-edge tiles masked).
// Constants: B=1 NW=8 SEG=511 S=4096 W=256 C=16 H=12 D=64 DM=768 FF=3072 L=12
// ---------------------------------------------------------------------------

typedef unsigned short u16;
typedef __attribute__((ext_vector_type(4))) float floatx4;
typedef __attribute__((ext_vector_type(4))) unsigned int uintx4;
typedef __attribute__((ext_vector_type(8))) short bf16x8;
typedef __attribute__((ext_vector_type(4))) u16 u16x4;

#define S_LEN 4096
#define QKVG_N 4608   // q(0) k(768) v(1536) kg(2304) vg(3072) qg(3840)
#define NL 12

__device__ inline u16 f2bf(float x) {
    union { __hip_bfloat16 b; u16 u; } cv;
    cv.b = __float2bfloat16(x);
    return cv.u;
}
__device__ inline float bf2f(u16 u) {
    union { float f; unsigned int i; } c; c.i = ((unsigned int)u) << 16; return c.f;
}
__device__ inline float gelu_f(float x) {
    float x3 = x * x * x;
    return 0.5f * x * (1.0f + tanhf(0.7978845608028654f * (x + 0.044715f * x3)));
}

#define GLDS16(g, l)                                                              \
    __builtin_amdgcn_global_load_lds(                                             \
        (const __attribute__((address_space(1))) unsigned int*)(g),               \
        (__attribute__((address_space(3))) unsigned int*)(l), 16, 0, 0)

// ---------------------------------------------------------------------------
// Weight prep v2, ALL layers in one launch: fp32 [K][N] -> bf16 [N][K].
// 64x64 tiles: float4 reads, transpose via [64][65] fp32 LDS (<=2-way banks),
// u16x4 (8B) coalesced writes (128B per 16 lanes). blockIdx.y = layer.
// Per-layer tiles: qkvg 6*144, wo 144, w1 576, w2 576 = 2160; +18 bias blocks.
// ---------------------------------------------------------------------------
__global__ __launch_bounds__(256) void prep_weights_k(
    const float* __restrict__ Wq0, const float* __restrict__ Wk0, const float* __restrict__ Wv0,
    const float* __restrict__ Wkg0, const float* __restrict__ Wvg0, const float* __restrict__ Wqg0,
    const float* __restrict__ Wo0, const float* __restrict__ W10, const float* __restrict__ W20,
    const float* __restrict__ bq0, const float* __restrict__ bk0, const float* __restrict__ bv0,
    const float* __restrict__ bkg0, const float* __restrict__ bvg0, const float* __restrict__ bqg0,
    u16* __restrict__ wTall, float* __restrict__ bcatall)
{
    const int l = blockIdx.y;
    const size_t sqo = (size_t)l * 589824;     // 768*768 fp32 stride
    const size_t sff = (size_t)l * 2359296;    // 768*3072 fp32 stride
    u16* wqkvgT = wTall + (size_t)l * 8847360;
    u16* woT = wqkvgT + 3538944;
    u16* w1T = woT + 589824;
    u16* w2T = w1T + 2359296;

    int bid = blockIdx.x;
    int t = threadIdx.x;
    if (bid >= 2160) {                        // bias concat tail: 4608 floats
        int i = (bid - 2160) * 256 + t;
        float v;
        if (i < 768)       v = bq0[l * 768 + i];
        else if (i < 1536) v = bk0[l * 768 + i - 768];
        else if (i < 2304) v = bv0[l * 768 + i - 1536];
        else if (i < 3072) v = bkg0[l * 768 + i - 2304];
        else if (i < 3840) v = bvg0[l * 768 + i - 3072];
        else               v = bqg0[l * 768 + i - 3840];
        bcatall[(size_t)l * 4608 + i] = v;
        return;
    }
    const float* src; u16* dst; int K, N, tile;
    if (bid < 864) {
        int m = bid / 144; tile = bid % 144;
        src = ((m == 0) ? Wq0 : (m == 1) ? Wk0 : (m == 2) ? Wv0 :
               (m == 3) ? Wkg0 : (m == 4) ? Wvg0 : Wqg0) + sqo;
        dst = wqkvgT + (size_t)m * 589824;
        K = 768; N = 768;
    } else if (bid < 1008) { tile = bid - 864;  src = Wo0 + sqo; dst = woT; K = 768;  N = 768; }
    else if (bid < 1584)   { tile = bid - 1008; src = W10 + sff; dst = w1T; K = 768;  N = 3072; }
    else                   { tile = bid - 1584; src = W20 + sff; dst = w2T; K = 3072; N = 768; }

    int nt = N >> 6;
    int k0 = (tile / nt) << 6, n0 = (tile % nt) << 6;
    __shared__ float tb[64][65];              // [n][k], 65-stride: <=2-way banks
    int r = t >> 4, c4 = (t & 15) * 4;        // read: row r+16j, 4 cols at c4
    #pragma unroll
    for (int j = 0; j < 4; j++) {
        int kk = r + j * 16;
        floatx4 v = *(const floatx4*)&src[(size_t)(k0 + kk) * N + n0 + c4];
        #pragma unroll
        for (int i = 0; i < 4; i++) tb[c4 + i][kk] = v[i];
    }
    __syncthreads();
    int k4 = (t & 15) * 4, nb = t >> 4;       // write: n = nb+16j, 4 ks at k4
    #pragma unroll
    for (int j = 0; j < 4; j++) {
        int n = nb + j * 16;
        u16x4 o;
        #pragma unroll
        for (int i = 0; i < 4; i++) o[i] = f2bf(tb[n][k4 + i]);
        *(u16x4*)&dst[(size_t)(n0 + n) * K + k0 + k4] = o;
    }
}

// ---------------------------------------------------------------------------
// bf16 MFMA GEMM, BK=64 (global_load_lds staging, m97 pattern, half the
// barrier count of BK=32).
// - XCD-bijective swizzle on the flattened (x,y) grid (gridDim.x == 32).
// - SKIPQG: qg N-tiles (by>=30) only needed where bm%512==0.
// - WVT: v-column tiles (cc in [1536,2304)) also write transposed vTg.
// - SPLITB: blockIdx.z = K-split; bias only added by z==0.
// All K call sites divisible by 64.
// ---------------------------------------------------------------------------
template <int ACT, int WF, int WB, int SKIPQG, int WVT, int SPLITB>
__global__ __launch_bounds__(256, 3) void gemm_k(
    const u16* __restrict__ A, const u16* __restrict__ Bt,
    const float* __restrict__ bias,
    float* __restrict__ Cf, u16* __restrict__ Cb, u16* __restrict__ vTg,
    int N, int K, int lda, int ldb)
{
    // XCD-bijective swizzle (nwg % 8 == 0 at every call site)
    int lin = blockIdx.y * 32 + blockIdx.x;
    int qq = gridDim.y << 2;                   // nwg/8 = 32*gy/8
    int wg = (lin & 7) * qq + (lin >> 3);
    int bx = wg & 31, by = wg >> 5;
    if (SKIPQG && by >= 30 && (bx & 3) != 0) return;
    int bm = bx * 128, bn = by * 128;
    const int zoff = SPLITB ? blockIdx.z : 0;
    const u16* Ab = A + (size_t)zoff * K;
    const u16* Bb = Bt + (size_t)zoff * K;
    float* Cfz = WF ? Cf + (size_t)zoff * S_LEN * N : (float*)nullptr;

    __shared__ __align__(16) u16 As[128][64];
    __shared__ __align__(16) u16 Bs[128][64];
    int t = threadIdx.x, lane = t & 63, wv = t >> 6;
    int wm = (wv >> 1) * 64, wn = (wv & 1) * 64;
    int srow = t >> 3, scol = (t & 7) * 8;     // staging: 32 rows/chunk x 64 cols
    int fr = lane & 15, fo = (lane >> 4) * 8;  // fragment row / k-offset

    floatx4 acc[4][4];
    #pragma unroll
    for (int i = 0; i < 4; i++)
        #pragma unroll
        for (int j = 0; j < 4; j++) acc[i][j] = (floatx4){0.f, 0.f, 0.f, 0.f};

    const int nk = K >> 6;
    for (int kt = 0; kt < nk; ++kt) {
        const u16* ag = Ab + (size_t)(bm + srow) * lda + kt * 64 + scol;
        const u16* bg = Bb + (size_t)(bn + srow) * ldb + kt * 64 + scol;
        #pragma unroll
        for (int c = 0; c < 4; ++c) {
            GLDS16(ag + (size_t)(32 * c) * lda, &As[srow + 32 * c][scol]);
            GLDS16(bg + (size_t)(32 * c) * ldb, &Bs[srow + 32 * c][scol]);
        }
        __syncthreads();
        #pragma unroll
        for (int ks = 0; ks < 2; ++ks) {
            bf16x8 af[4], bfr[4];
            #pragma unroll
            for (int i = 0; i < 4; i++) af[i]  = *(const bf16x8*)&As[wm + i * 16 + fr][ks * 32 + fo];
            #pragma unroll
            for (int i = 0; i < 4; i++) bfr[i] = *(const bf16x8*)&Bs[wn + i * 16 + fr][ks * 32 + fo];
            #pragma unroll
            for (int i = 0; i < 4; i++)
                #pragma unroll
                for (int j = 0; j < 4; j++)
                    acc[i][j] = __builtin_amdgcn_mfma_f32_16x16x32_bf16(af[i], bfr[j], acc[i][j], 0, 0, 0);
        }
        __syncthreads();
    }

    int dr = (lane >> 4) * 4, dc = lane & 15;
    #pragma unroll
    for (int i = 0; i < 4; i++) {
        #pragma unroll
        for (int j = 0; j < 4; j++) {
            int r0 = bm + wm + i * 16 + dr;
            int cc = bn + wn + j * 16 + dc;
            float bsv = (!SPLITB || blockIdx.z == 0) ? bias[cc] : 0.f;
            u16x4 tv;
            #pragma unroll
            for (int r = 0; r < 4; r++) {
                float v = acc[i][j][r] + bsv;
                if (ACT == 1) v = gelu_f(v);
                if (WF) Cfz[(size_t)(r0 + r) * N + cc] = v;
                if (WB) { u16 b = f2bf(v); Cb[(size_t)(r0 + r) * N + cc] = b; tv[r] = b; }
            }
            if (WVT && cc >= 1536 && cc < 2304)
                *(u16x4*)&vTg[(size_t)(cc - 1536) * 4096 + r0] = tv;
        }
    }
}

// ---------------------------------------------------------------------------
// MFMA local banded attention + joint softmax with 8 global CLS keys.
// grid (64 q-tiles, 12 heads) with XCD swizzle. 4 waves x 16 queries;
// computes S^T via mfma(K, Q); PV uses pre-transposed V (vTg).
// Tile 0 = 8 global CLS keys. Surviving local tiles always have
// kbase in [0, 4032] (uniform skip), so staging needs no clamps and only
// tiles 1/9 (|offset|=256) need the band mask.
// ---------------------------------------------------------------------------
__global__ __launch_bounds__(256) void attn_local_k(
    const u16* __restrict__ qkvg, const u16* __restrict__ vTg, u16* __restrict__ aob)
{
    int lin = blockIdx.y * 64 + blockIdx.x;   // nwg = 768
    int wg = (lin & 7) * 96 + (lin >> 3);
    const int qb = wg & 63, hh = wg >> 6;
    const int t = threadIdx.x, lane = t & 63, w = t >> 6;
    const int g = lane >> 4, qi = lane & 15;
    __shared__ __align__(16) u16 ks[64][72];
    __shared__ __align__(16) u16 vt[64][72];
    __shared__ __align__(16) u16 pbuf[4][16][40];

    const int q0w = qb * 64 + w * 16;
    const int sq = q0w + qi;                 // softmax-column query (per lane)

    bf16x8 qf0, qf1;                          // Q B-operand frags (2 k-steps)
    {
        const u16* qp = qkvg + (size_t)(q0w + qi) * QKVG_N + hh * 64 + g * 8;
        qf0 = *(const bf16x8*)qp;
        qf1 = *(const bf16x8*)(qp + 32);
    }

    floatx4 acc[4];
    #pragma unroll
    for (int i = 0; i < 4; i++) acc[i] = (floatx4){0.f, 0.f, 0.f, 0.f};
    float mrun = -1e30f, lrun = 0.f;

    for (int tile = 0; tile <= 9; ++tile) {
        const int kbase = qb * 64 - 256 + (tile - 1) * 64;
        if (tile > 0 && (kbase < 0 || kbase >= S_LEN)) continue;  // uniform skip
        __syncthreads();
        if (tile == 0) {
            // zero vt (avoid NaN junk x P=0), then fill 8 global K/V columns
            for (int i = t; i < 576; i += 256) ((uintx4*)vt)[i] = (uintx4){0, 0, 0, 0};
            __syncthreads();
            if (t < 64) {
                int gg = t >> 3, d0 = (t & 7) * 8;
                *(uintx4*)&ks[gg][d0] =
                    *(const uintx4*)(qkvg + (size_t)(gg * 512) * QKVG_N + 768 + hh * 64 + d0);
            }
            for (int e = t; e < 512; e += 256) {
                int d = e >> 3, gg = e & 7;
                vt[d][gg] = vTg[(size_t)(hh * 64 + d) * 4096 + gg * 512];
            }
        } else {
            for (int c = t; c < 512; c += 256) {
                int r = c >> 3, c0 = (c & 7) * 8;
                *(uintx4*)&ks[r][c0] =
                    *(const uintx4*)(qkvg + (size_t)(kbase + r) * QKVG_N + 768 + hh * 64 + c0);
                *(uintx4*)&vt[r][c0] =
                    *(const uintx4*)(vTg + (size_t)(hh * 64 + r) * 4096 + kbase + c0);
            }
        }
        __syncthreads();

        const bool gt = (tile == 0);
        const bool edge = (tile == 1) | (tile == 9);
        const int ng = gt ? 1 : 2;
        for (int kg2 = 0; kg2 < ng; ++kg2) {
            floatx4 sf[2];
            sf[1] = (floatx4){0.f, 0.f, 0.f, 0.f};
            {
                bf16x8 ka0 = *(const bf16x8*)&ks[kg2 * 32 + qi][g * 8];
                bf16x8 ka1 = *(const bf16x8*)&ks[kg2 * 32 + qi][32 + g * 8];
                floatx4 z = (floatx4){0.f, 0.f, 0.f, 0.f};
                z = __builtin_amdgcn_mfma_f32_16x16x32_bf16(ka0, qf0, z, 0, 0, 0);
                sf[0] = __builtin_amdgcn_mfma_f32_16x16x32_bf16(ka1, qf1, z, 0, 0, 0);
            }
            if (!gt) {
                bf16x8 kb0 = *(const bf16x8*)&ks[kg2 * 32 + 16 + qi][g * 8];
                bf16x8 kb1 = *(const bf16x8*)&ks[kg2 * 32 + 16 + qi][32 + g * 8];
                floatx4 z = (floatx4){0.f, 0.f, 0.f, 0.f};
                z = __builtin_amdgcn_mfma_f32_16x16x32_bf16(kb0, qf0, z, 0, 0, 0);
                sf[1] = __builtin_amdgcn_mfma_f32_16x16x32_bf16(kb1, qf1, z, 0, 0, 0);
            }
            // scores: lane holds keys kl = kg2*32 + f*16 + g*4 + r for query sq
            float p8[8];
            float mloc = -1e30f;
            #pragma unroll
            for (int f = 0; f < 2; ++f)
                #pragma unroll
                for (int r = 0; r < 4; ++r) {
                    int kl = kg2 * 32 + f * 16 + g * 4 + r;
                    float sc = sf[f][r] * 0.125f;
                    if (gt) {
                        if (kl >= 8) sc = -1e30f;
                    } else if (edge) {
                        int dd = kbase + kl - sq;
                        if (dd > 256 || dd < -256) sc = -1e30f;
                    }
                    p8[f * 4 + r] = sc;
                    mloc = fmaxf(mloc, sc);
                }
            mloc = fmaxf(mloc, __shfl_xor(mloc, 16));
            mloc = fmaxf(mloc, __shfl_xor(mloc, 32));
            float mnew = fmaxf(mrun, mloc);
            float alpha = __expf(mrun - mnew);
            mrun = mnew;
            float ls = 0.f;
            #pragma unroll
            for (int i = 0; i < 8; ++i) { float p = __expf(p8[i] - mnew); p8[i] = p; ls += p; }
            ls += __shfl_xor(ls, 16);
            ls += __shfl_xor(ls, 32);
            lrun = lrun * alpha + ls;
            // pack P -> wave-private LDS (row q=qi, cols f*16 + g*4 ..+3)
            u16x4 w0, w1;
            #pragma unroll
            for (int r = 0; r < 4; ++r) { w0[r] = f2bf(p8[r]); w1[r] = f2bf(p8[4 + r]); }
            *(u16x4*)&pbuf[w][qi][g * 4] = w0;
            *(u16x4*)&pbuf[w][qi][16 + g * 4] = w1;
            // rescale acc rows (row m = g*4+r, alpha lives at lane m)
            float al[4];
            #pragma unroll
            for (int r = 0; r < 4; ++r) al[r] = __shfl(alpha, g * 4 + r);
            #pragma unroll
            for (int dt = 0; dt < 4; ++dt)
                #pragma unroll
                for (int r = 0; r < 4; ++r) acc[dt][r] *= al[r];
            // P A-frag + PV MFMAs
            bf16x8 pf = *(const bf16x8*)&pbuf[w][qi][g * 8];
            #pragma unroll
            for (int dt = 0; dt < 4; ++dt) {
                bf16x8 vb = *(const bf16x8*)&vt[dt * 16 + qi][kg2 * 32 + g * 8];
                acc[dt] = __builtin_amdgcn_mfma_f32_16x16x32_bf16(pf, vb, acc[dt], 0, 0, 0);
            }
        }
    }

    float inv = 1.f / lrun;
    float li[4];
    #pragma unroll
    for (int r = 0; r < 4; ++r) li[r] = __shfl(inv, g * 4 + r);
    #pragma unroll
    for (int dt = 0; dt < 4; ++dt)
        #pragma unroll
        for (int r = 0; r < 4; ++r) {
            int s = q0w + g * 4 + r;
            aob[(size_t)s * 768 + hh * 64 + dt * 16 + qi] = f2bf(acc[dt][r] * li[r]);
        }
}

// ---------------------------------------------------------------------------
// LayerNorm helpers
// ---------------------------------------------------------------------------
#define BLOCK_MEANVAR(sum, sq, mean, inv)                                        \
    {                                                                            \
        for (int o_ = 32; o_ > 0; o_ >>= 1) {                                    \
            sum += __shfl_down(sum, o_); sq += __shfl_down(sq, o_);              \
        }                                                                        \
        __shared__ float rs_[4], rq_[4];                                         \
        if ((threadIdx.x & 63) == 0) { rs_[threadIdx.x >> 6] = sum; rq_[threadIdx.x >> 6] = sq; } \
        __syncthreads();                                                         \
        float S_ = rs_[0] + rs_[1] + rs_[2] + rs_[3];                            \
        float Q_ = rq_[0] + rq_[1] + rq_[2] + rq_[3];                            \
        mean = S_ * (1.f / 768.f);                                               \
        float var_ = Q_ * (1.f / 768.f) - mean * mean;                           \
        inv = rsqrtf(var_ + 1e-5f);                                              \
    }

__global__ __launch_bounds__(256) void embed_ln_k(
    const int* __restrict__ x, const float* __restrict__ wemb, const float* __restrict__ pemb,
    const float* __restrict__ gs, const float* __restrict__ gb,
    float* __restrict__ hf, u16* __restrict__ hb)
{
    int s = blockIdx.x, t = threadIdx.x;
    int w = s >> 9, p = s & 511;
    int id = (p == 0) ? 0 : x[w * 511 + p - 1];
    float v[3], sum = 0.f, sq = 0.f;
    #pragma unroll
    for (int r = 0; r < 3; r++) {
        int d = t + r * 256;
        float e = wemb[(size_t)id * 768 + d] + pemb[(size_t)s * 768 + d];
        v[r] = e; sum += e; sq += e * e;
    }
    float mean, inv;
    BLOCK_MEANVAR(sum, sq, mean, inv)
    #pragma unroll
    for (int r = 0; r < 3; r++) {
        int d = t + r * 256;
        float y = (v[r] - mean) * inv * gs[d] + gb[d];
        hf[(size_t)s * 768 + d] = y;
        hb[(size_t)s * 768 + d] = f2bf(y);
    }
}

// of = LN(xa + xb + xc): xb/xc are the two split-K GEMM partial outputs.
__global__ __launch_bounds__(256) void ln_resid_k(
    const float* __restrict__ xa, const float* __restrict__ xb, const float* __restrict__ xc,
    const float* __restrict__ gs, const float* __restrict__ gb,
    float* __restrict__ of, u16* __restrict__ ob)
{
    int s = blockIdx.x, t = threadIdx.x;
    const float* pa = xa + (size_t)s * 768;
    const float* pb = xb + (size_t)s * 768;
    const float* pc = xc + (size_t)s * 768;
    float v[3], sum = 0.f, sq = 0.f;
    #pragma unroll
    for (int r = 0; r < 3; r++) {
        int d = t + r * 256;
        float e = pa[d] + pb[d] + pc[d];
        v[r] = e; sum += e; sq += e * e;
    }
    float mean, inv;
    BLOCK_MEANVAR(sum, sq, mean, inv)
    #pragma unroll
    for (int r = 0; r < 3; r++) {
        int d = t + r * 256;
        float y = (v[r] - mean) * inv * gs[d] + gb[d];
        of[(size_t)s * 768 + d] = y;
        ob[(size_t)s * 768 + d] = f2bf(y);
    }
}

// ---------------------------------------------------------------------------
// Global-token attention, pass 1: split-K partials.
// grid (12 heads, 32 key-chunks of 128), 256 threads.
// qg read directly from fused projection output (bf16, scaled here).
// ---------------------------------------------------------------------------
__global__ __launch_bounds__(256) void attn_gpart_k(
    const u16* __restrict__ qkvg,
    float* __restrict__ pacc, float* __restrict__ pm, float* __restrict__ pl)
{
    const int hh = blockIdx.x, ck = blockIdx.y;
    const int t = threadIdx.x;
    __shared__ float qs[8][64];
    __shared__ __align__(16) u16 ks[128][72];   // +8 pad: stage writes c-free
    __shared__ __align__(16) u16 vs[128][64];   // read d-major -> conflict-free
    __shared__ float sc[8][128];
    __shared__ float mred[8], lred[8];

    for (int i = t; i < 512; i += 256) {
        int g = i >> 6, d = i & 63;
        qs[g][d] = bf2f(qkvg[(size_t)(g * 512) * QKVG_N + 3840 + hh * 64 + d]) * 0.125f;
    }
    const int s0 = ck * 128;
    for (int u = t; u < 1024; u += 256) {
        int r = u >> 3, c = u & 7;
        const u16* src = qkvg + (size_t)(s0 + r) * QKVG_N + hh * 64 + c * 8;
        *(uintx4*)&ks[r][c * 8] = *(const uintx4*)(src + 2304);
        *(uintx4*)&vs[r][c * 8] = *(const uintx4*)(src + 3072);
    }
    __syncthreads();

    // scores: thread (key = t&127) computes 4 queries (t>>7 selects 0-3 / 4-7)
    {
        int key = t & 127, q0 = (t >> 7) * 4;
        float a[4] = {0.f, 0.f, 0.f, 0.f};
        #pragma unroll
        for (int c = 0; c < 8; ++c) {
            uintx4 pk = *(const uintx4*)&ks[key][c * 8];
            const u16* uu = (const u16*)&pk;
            #pragma unroll
            for (int e = 0; e < 8; ++e) {
                float kv = bf2f(uu[e]);
                #pragma unroll
                for (int q = 0; q < 4; ++q) a[q] += kv * qs[q0 + q][c * 8 + e];
            }
        }
        #pragma unroll
        for (int q = 0; q < 4; ++q) sc[q0 + q][key] = a[q];
    }
    __syncthreads();

    // chunk softmax: q = t>>5, 32 lanes/query, 4 keys each
    {
        int q = t >> 5, lq = t & 31;
        float m = -1e30f;
        #pragma unroll
        for (int i = 0; i < 4; ++i) m = fmaxf(m, sc[q][lq + i * 32]);
        #pragma unroll
        for (int o = 1; o < 32; o <<= 1) m = fmaxf(m, __shfl_xor(m, o));
        float ls = 0.f;
        #pragma unroll
        for (int i = 0; i < 4; ++i) {
            float p = __expf(sc[q][lq + i * 32] - m);
            sc[q][lq + i * 32] = p; ls += p;
        }
        #pragma unroll
        for (int o = 1; o < 32; o <<= 1) ls += __shfl_xor(ls, o);
        if (lq == 0) { mred[q] = m; lred[q] = ls; }
    }
    __syncthreads();

    // partial PV: thread (d = t&63, qb = t>>6) -> o[qb][d], o[qb+4][d]
    {
        int d = t & 63, qb = t >> 6;
        float a0 = 0.f, a1 = 0.f;
        #pragma unroll 4
        for (int s = 0; s < 128; ++s) {
            float v = bf2f(vs[s][d]);
            a0 += sc[qb][s] * v;
            a1 += sc[qb + 4][s] * v;
        }
        float* pb = pacc + (((size_t)hh * 32 + ck) * 8) * 64;
        pb[qb * 64 + d] = a0;
        pb[(qb + 4) * 64 + d] = a1;
        if (t < 8) {
            pm[((size_t)hh * 32 + ck) * 8 + t] = mred[t];
            pl[((size_t)hh * 32 + ck) * 8 + t] = lred[t];
        }
    }
}

// Pass 2: merge 32 chunk partials per (head, query), overwrite GPOS rows.
__global__ __launch_bounds__(64) void attn_gred_k(
    const float* __restrict__ pacc, const float* __restrict__ pm,
    const float* __restrict__ pl, u16* __restrict__ aob)
{
    int hh = blockIdx.x, gq = blockIdx.y;
    int d = threadIdx.x;
    float M = -1e30f;
    #pragma unroll 4
    for (int c = 0; c < 32; ++c)
        M = fmaxf(M, pm[((size_t)hh * 32 + c) * 8 + gq]);
    float L = 0.f, o = 0.f;
    #pragma unroll 4
    for (int c = 0; c < 32; ++c) {
        float w = __expf(pm[((size_t)hh * 32 + c) * 8 + gq] - M);
        L += pl[((size_t)hh * 32 + c) * 8 + gq] * w;
        o += w * pacc[(((size_t)hh * 32 + c) * 8 + gq) * 64 + d];
    }
    aob[(size_t)(gq * 512) * 768 + hh * 64 + d] = f2bf(o / L);
}

__global__ __launch_bounds__(128) void head_k(
    const float* __restrict__ hf, const float* __restrict__ Wout,
    const float* __restrict__ bout, float* __restrict__ out)
{
    int g = blockIdx.x, n = threadIdx.x;
    __shared__ float hsh[768];
    for (int i = n; i < 768; i += 128) hsh[i] = hf[(size_t)(g * 512) * 768 + i];
    __syncthreads();
    float a = 0.f;
    #pragma unroll 4
    for (int k = 0; k < 768; k++) a += hsh[k] * Wout[k * 128 + n];
    out[g * 128 + n] = a + bout[n];
}

// ---------------------------------------------------------------------------
extern "C" void kernel_launch(void* const* d_in, const int* in_sizes, int n_in,
                              void* d_out, int out_size, void* d_ws, size_t ws_size,
                              hipStream_t stream)
{
    (void)in_sizes; (void)n_in; (void)out_size; (void)ws_size;
    const int*   x    = (const int*)  d_in[0];
    const float* wemb = (const float*)d_in[1];
    const float* pemb = (const float*)d_in[2];
    const float* elns = (const float*)d_in[3];
    const float* elnb = (const float*)d_in[4];
    const float* Wq   = (const float*)d_in[5];
    const float* bq   = (const float*)d_in[6];
    const float* Wk   = (const float*)d_in[7];
    const float* bk   = (const float*)d_in[8];
    const float* Wv   = (const float*)d_in[9];
    const float* bv   = (const float*)d_in[10];
    const float* Wo   = (const float*)d_in[11];
    const float* bo   = (const float*)d_in[12];
    const float* Wqg  = (const float*)d_in[13];
    const float* bqg  = (const float*)d_in[14];
    const float* Wkg  = (const float*)d_in[15];
    const float* bkg  = (const float*)d_in[16];
    const float* Wvg  = (const float*)d_in[17];
    const float* bvg  = (const float*)d_in[18];
    const float* l1s  = (const float*)d_in[19];
    const float* l1b  = (const float*)d_in[20];
    const float* W1   = (const float*)d_in[21];
    const float* b1   = (const float*)d_in[22];
    const float* W2   = (const float*)d_in[23];
    const float* b2   = (const float*)d_in[24];
    const float* l2s  = (const float*)d_in[25];
    const float* l2b  = (const float*)d_in[26];
    const float* Wout = (const float*)d_in[27];
    const float* boutp= (const float*)d_in[28];

    char* W = (char*)d_ws;
    float* hf    = (float*)(W);                  // [4096][768]  fp32
    u16*   hb    = (u16*)  (W + 12582912);       // [4096][768]  bf16
    u16*   qkvg  = (u16*)  (W + 18874368);       // [4096][4608] bf16
    u16*   vTg   = (u16*)  (W + 56623104);       // [768][4096]  bf16
    u16*   aob   = (u16*)  (W + 62914560);       // [4096][768]  bf16
    float* yf    = (float*)(W + 69206016);       // [2][4096][768] fp32 split slabs
    u16*   ff1b  = (u16*)  (W + 94371840);       // [4096][3072] bf16
    float* pacc  = (float*)(W + 119537664);      // [12][32][8][64] fp32
    float* pmw   = (float*)(W + 120324096);      // [12][32][8]     fp32
    float* plw   = (float*)(W + 120336384);      // [12][32][8]     fp32
    float* bcatall = (float*)(W + 120348672);    // [12][4608]      fp32
    u16*   wTall = (u16*)  (W + 120569856);      // [12] x 8847360 u16

    // All-layer weight prep (one launch)
    prep_weights_k<<<dim3(2178, 12), 256, 0, stream>>>(
        Wq, Wk, Wv, Wkg, Wvg, Wqg, Wo, W1, W2,
        bq, bk, bv, bkg, bvg, bqg, wTall, bcatall);

    embed_ln_k<<<4096, 256, 0, stream>>>(x, wemb, pemb, elns, elnb, hf, hb);

    float* yf0 = yf;
    float* yf1 = yf + (size_t)4096 * 768;

    for (int l = 0; l < NL; ++l) {
        u16* wTl      = wTall + (size_t)l * 8847360;
        u16* wqkvgT_l = wTl;
        u16* woT_l    = wTl + 3538944;
        u16* w1T_l    = woT_l + 589824;
        u16* w2T_l    = w1T_l + 2359296;
        float* bcat_l = bcatall + (size_t)l * 4608;
        const float* bo_l  = bo  + (size_t)l * 768;
        const float* b1_l  = b1  + (size_t)l * 3072;
        const float* b2_l  = b2  + (size_t)l * 768;
        const float* l1s_l = l1s + (size_t)l * 768;
        const float* l1b_l = l1b + (size_t)l * 768;
        const float* l2s_l = l2s + (size_t)l * 768;
        const float* l2b_l = l2b + (size_t)l * 768;

        // fused q/k/v/kg/vg/qg projection -> bf16 [4096][4608] (+ vTg fused)
        gemm_k<0, 0, 1, 1, 1, 0><<<dim3(32, 36), 256, 0, stream>>>(
            hb, wqkvgT_l, bcat_l, (float*)nullptr, qkvg, vTg, QKVG_N, 768, 768, 768);

        attn_local_k<<<dim3(64, 12), 256, 0, stream>>>(qkvg, vTg, aob);

        attn_gpart_k<<<dim3(12, 32), 256, 0, stream>>>(qkvg, pacc, pmw, plw);
        attn_gred_k<<<dim3(12, 8), 64, 0, stream>>>(pacc, pmw, plw, aob);

        // attention output proj, split-K x2 (K=384 each)
        gemm_k<0, 1, 0, 0, 0, 1><<<dim3(32, 6, 2), 256, 0, stream>>>(
            aob, woT_l, bo_l, yf, (u16*)nullptr, (u16*)nullptr, 768, 384, 768, 768);
        ln_resid_k<<<4096, 256, 0, stream>>>(hf, yf0, yf1, l1s_l, l1b_l, hf, hb);

        gemm_k<1, 0, 1, 0, 0, 0><<<dim3(32, 24), 256, 0, stream>>>(
            hb, w1T_l, b1_l, (float*)nullptr, ff1b, (u16*)nullptr, 3072, 768, 768, 768);
        // FFN down proj, split-K x2 (K=1536 each)
        gemm_k<0, 1, 0, 0, 0, 1><<<dim3(32, 6, 2), 256, 0, stream>>>(
            ff1b, w2T_l, b2_l, yf, (u16*)nullptr, (u16*)nullptr, 768, 1536, 3072, 3072);
        ln_resid_k<<<4096, 256, 0, stream>>>(hf, yf0, yf1, l2s_l, l2b_l, hf, hb);
    }

    head_k<<<8, 128, 0, stream>>>(hf, Wout, boutp, (float*)d_out);
}